// Round 4
// baseline (610.631 us; speedup 1.0000x reference)
//
#include <hip/hip_runtime.h>

#define N_NODES 50000
#define N_EDGES 800000
#define N_GRAPHS 64
#define F 256        // F_IN == F_HID
#define F_OUT 128
#define G_DIM 768    // 3*F
#define SCAN_NB ((N_NODES + 255) / 256)   // 196
#define POOL_CHUNKS 32

typedef unsigned short ushort_t;
typedef short short8 __attribute__((ext_vector_type(8)));
typedef unsigned short ushort8 __attribute__((ext_vector_type(8)));
typedef unsigned short ushort4v __attribute__((ext_vector_type(4)));
typedef float float4v __attribute__((ext_vector_type(4)));

// ---- bf16 helpers (RNE) ----
__device__ __forceinline__ unsigned short f2bf(float f) {
    unsigned int u = __float_as_uint(f);
    u += 0x7FFFu + ((u >> 16) & 1u);
    return (unsigned short)(u >> 16);
}
__device__ __forceinline__ float bf2f(unsigned short s) {
    return __uint_as_float(((unsigned int)s) << 16);
}

// ---- async global->LDS, 16B per lane; LDS dest = wave-uniform base + lane*16 ----
__device__ __forceinline__ void gld_lds16(const void* gsrc, void* ldst) {
    __builtin_amdgcn_global_load_lds(
        (const __attribute__((address_space(1))) unsigned int*)gsrc,
        (__attribute__((address_space(3))) unsigned int*)ldst, 16, 0, 0);
}

// ---------------- fused: W1/W2 transposed hi/lo cast (blocks 0..511) + degree count ----------------
__global__ void prep_w_deg(const float* __restrict__ W1, const float* __restrict__ W2,
                           short* __restrict__ hi1, short* __restrict__ lo1,
                           short* __restrict__ hi2, short* __restrict__ lo2,
                           const int* __restrict__ dst, int* __restrict__ deg) {
    int blk = blockIdx.x;
    if (blk < 512) {
        const float* W = (blk < 256) ? W1 : W2;
        short* hi = (blk < 256) ? hi1 : hi2;
        short* lo = (blk < 256) ? lo1 : lo2;
        int n = blk & 255;
        int k = threadIdx.x;
        float v = W[k * 256 + n];
        unsigned short h = f2bf(v);
        hi[n * 256 + k] = (short)h;
        lo[n * 256 + k] = (short)f2bf(v - bf2f(h));
    } else {
        int e = (blk - 512) * 256 + threadIdx.x;
        if (e < N_EDGES) atomicAdd(&deg[dst[e]], 1);
    }
}

// ---------------- scan blocks + fused dinv (btot holds RAW per-block sums) ----------------
__global__ void scan_blocks(const int* __restrict__ deg, int* __restrict__ row_ptr,
                            int* __restrict__ block_tot, float* __restrict__ dinv) {
    __shared__ int sd[256];
    int t = threadIdx.x;
    int idx = blockIdx.x * 256 + t;
    int v = (idx < N_NODES) ? deg[idx] : 0;
    if (idx < N_NODES) dinv[idx] = rsqrtf((float)(v + 1));   // +1 self-loop
    sd[t] = v;
    __syncthreads();
    for (int off = 1; off < 256; off <<= 1) {
        int a = (t >= off) ? sd[t - off] : 0;
        __syncthreads();
        sd[t] += a;
        __syncthreads();
    }
    if (idx < N_NODES) row_ptr[idx] = sd[t] - v;
    if (t == 255) block_tot[blockIdx.x] = sd[255];
}

// ---------------- add block offsets; each block reduces btot[0..blk) itself ----------------
__global__ void add_offsets(int* __restrict__ row_ptr, const int* __restrict__ block_tot) {
    __shared__ int sd[256];
    int t = threadIdx.x;
    int blk = blockIdx.x;
    sd[t] = (t < blk && t < SCAN_NB) ? block_tot[t] : 0;
    __syncthreads();
    for (int off = 128; off > 0; off >>= 1) {
        if (t < off) sd[t] += sd[t + off];
        __syncthreads();
    }
    int base = sd[0];
    int idx = blk * 256 + t;
    if (idx < N_NODES) row_ptr[idx] += base;
    if (idx == 0) row_ptr[N_NODES] = N_EDGES;
}

// ---------------- bucket edges into CSR order; packed 4B record ----------------
// erec[pos] = src (low 16) | bf16(norm) (high 16)
__global__ void bucket_edges(const int* __restrict__ src, const int* __restrict__ dst,
                             const float* __restrict__ dinv,
                             const int* __restrict__ row_ptr, int* __restrict__ cursor,
                             unsigned int* __restrict__ erec) {
    int e = blockIdx.x * blockDim.x + threadIdx.x;
    if (e < N_EDGES) {
        int d = dst[e];
        int s = src[e];
        int pos = row_ptr[d] + atomicAdd(&cursor[d], 1);
        unsigned int w = (unsigned int)f2bf(dinv[s] * dinv[d]);
        erec[pos] = (unsigned int)s | (w << 16);
    }
}

// ---------------- GEMM1: split-bf16 MFMA, fp32 A, A-prefetch pipeline ----------------
// hbf[M,256] = bf16( A[M,256] @ W[256,256] ); A fp32 row-major, W transposed hi/lo bf16.
#define BM 64
#define BK 32
__global__ __launch_bounds__(256) void gemm_mfma(
        const float* __restrict__ A,
        const short* __restrict__ Bthi, const short* __restrict__ Btlo,
        ushort_t* __restrict__ hbf, int M) {
    __shared__ short sAh[BM * BK], sAl[BM * BK];       // 4KB + 4KB
    __shared__ short sBh[256 * BK], sBl[256 * BK];     // 16KB + 16KB
    int tid = threadIdx.x;
    int wave = tid >> 6, lane = tid & 63;
    int q = lane >> 4, t = lane & 15;
    int row0 = blockIdx.x * BM;
    int wc = wave * 64;            // wave's 64-col slice of N=256

    int lrow = lane >> 2;          // 0..15 (B staging)
    int lk = (lane & 3) * 8;       // k offset (shorts)
    int ar = tid >> 2;             // A staging: row 0..63
    int ak = (tid & 3) * 8;        // A staging: 8 floats at kt+ak

    int ga = row0 + ar; if (ga >= M) ga = M - 1;       // clamp; never stored
    const float* abase = &A[(size_t)ga * 256 + ak];
    float4 a0 = *(const float4*)(abase);
    float4 a1 = *(const float4*)(abase + 4);

    float4v acc[4][4] = {};
    for (int kt = 0; kt < 256; kt += BK) {
#pragma unroll
        for (int j = 0; j < 4; ++j) {
            int n = wave * 64 + j * 16 + lrow;
            size_t boff = (size_t)n * 256 + kt + lk;
            int ldso = wave * 2048 + j * 512 + lane * 8;
            gld_lds16(&Bthi[boff], &sBh[ldso]);
            gld_lds16(&Btlo[boff], &sBl[ldso]);
        }
        {
            short8 h, l;
            unsigned short hh;
            hh = f2bf(a0.x); h[0] = (short)hh; l[0] = (short)f2bf(a0.x - bf2f(hh));
            hh = f2bf(a0.y); h[1] = (short)hh; l[1] = (short)f2bf(a0.y - bf2f(hh));
            hh = f2bf(a0.z); h[2] = (short)hh; l[2] = (short)f2bf(a0.z - bf2f(hh));
            hh = f2bf(a0.w); h[3] = (short)hh; l[3] = (short)f2bf(a0.w - bf2f(hh));
            hh = f2bf(a1.x); h[4] = (short)hh; l[4] = (short)f2bf(a1.x - bf2f(hh));
            hh = f2bf(a1.y); h[5] = (short)hh; l[5] = (short)f2bf(a1.y - bf2f(hh));
            hh = f2bf(a1.z); h[6] = (short)hh; l[6] = (short)f2bf(a1.z - bf2f(hh));
            hh = f2bf(a1.w); h[7] = (short)hh; l[7] = (short)f2bf(a1.w - bf2f(hh));
            *(short8*)&sAh[ar * BK + ak] = h;
            *(short8*)&sAl[ar * BK + ak] = l;
        }
        float4 na0 = a0, na1 = a1;
        if (kt + BK < 256) {
            na0 = *(const float4*)(abase + kt + BK);
            na1 = *(const float4*)(abase + kt + BK + 4);
        }
        __syncthreads();
        short8 ah[4], al[4], bh[4], bl[4];
#pragma unroll
        for (int mi = 0; mi < 4; ++mi) {
            int r = mi * 16 + t;
            ah[mi] = *(const short8*)&sAh[r * BK + q * 8];
            al[mi] = *(const short8*)&sAl[r * BK + q * 8];
        }
#pragma unroll
        for (int ni = 0; ni < 4; ++ni) {
            int n = wc + ni * 16 + t;
            bh[ni] = *(const short8*)&sBh[n * BK + q * 8];
            bl[ni] = *(const short8*)&sBl[n * BK + q * 8];
        }
#pragma unroll
        for (int mi = 0; mi < 4; ++mi)
#pragma unroll
            for (int ni = 0; ni < 4; ++ni) {
                acc[mi][ni] = __builtin_amdgcn_mfma_f32_16x16x32_bf16(ah[mi], bh[ni], acc[mi][ni], 0, 0, 0);
                acc[mi][ni] = __builtin_amdgcn_mfma_f32_16x16x32_bf16(ah[mi], bl[ni], acc[mi][ni], 0, 0, 0);
                acc[mi][ni] = __builtin_amdgcn_mfma_f32_16x16x32_bf16(al[mi], bh[ni], acc[mi][ni], 0, 0, 0);
            }
        __syncthreads();
        a0 = na0; a1 = na1;
    }
#pragma unroll
    for (int mi = 0; mi < 4; ++mi) {
        int gr0 = row0 + mi * 16 + q * 4;
#pragma unroll
        for (int rr = 0; rr < 4; ++rr) {
            int gr = gr0 + rr;
            if (gr < M) {
#pragma unroll
                for (int ni = 0; ni < 4; ++ni)
                    hbf[(size_t)gr * 256 + wc + ni * 16 + t] = f2bf(acc[mi][ni][rr]);
            }
        }
    }
}

// ---------------- GEMM2: bf16 A fully preloaded to regs; 2 MFMAs ----------------
__global__ __launch_bounds__(256) void gemm_mfma_bf16(
        const ushort_t* __restrict__ A,   // [M,256] bf16
        const short* __restrict__ Bthi, const short* __restrict__ Btlo,
        ushort_t* __restrict__ hbf, int M) {
    __shared__ short sA[BM * BK];                      // 4KB
    __shared__ short sBh[256 * BK], sBl[256 * BK];     // 16KB + 16KB
    int tid = threadIdx.x;
    int wave = tid >> 6, lane = tid & 63;
    int q = lane >> 4, t = lane & 15;
    int row0 = blockIdx.x * BM;
    int wc = wave * 64;

    int lrow = lane >> 2;          // 0..15 (B staging)
    int lk = (lane & 3) * 8;       // k offset (shorts)
    int ar = tid >> 2;             // A staging: row 0..63
    int ak = (tid & 3) * 8;        // 8 shorts at kt+ak

    int ga = row0 + ar; if (ga >= M) ga = M - 1;
    const ushort_t* abase = &A[(size_t)ga * 256 + ak];
    // preload ALL of this thread's A (8 x 16B = 1 HBM round-trip, issued together)
    ushort8 areg[8];
#pragma unroll
    for (int i = 0; i < 8; ++i) areg[i] = *(const ushort8*)(abase + i * BK);

    float4v acc[4][4] = {};
#pragma unroll
    for (int ki = 0; ki < 8; ++ki) {
        int kt = ki * BK;
#pragma unroll
        for (int j = 0; j < 4; ++j) {
            int n = wave * 64 + j * 16 + lrow;
            size_t boff = (size_t)n * 256 + kt + lk;
            int ldso = wave * 2048 + j * 512 + lane * 8;
            gld_lds16(&Bthi[boff], &sBh[ldso]);
            gld_lds16(&Btlo[boff], &sBl[ldso]);
        }
        *(ushort8*)&sA[ar * BK + ak] = areg[ki];
        __syncthreads();
        short8 ah[4], bh[4], bl[4];
#pragma unroll
        for (int mi = 0; mi < 4; ++mi) {
            int r = mi * 16 + t;
            ah[mi] = *(const short8*)&sA[r * BK + q * 8];
        }
#pragma unroll
        for (int ni = 0; ni < 4; ++ni) {
            int n = wc + ni * 16 + t;
            bh[ni] = *(const short8*)&sBh[n * BK + q * 8];
            bl[ni] = *(const short8*)&sBl[n * BK + q * 8];
        }
#pragma unroll
        for (int mi = 0; mi < 4; ++mi)
#pragma unroll
            for (int ni = 0; ni < 4; ++ni) {
                acc[mi][ni] = __builtin_amdgcn_mfma_f32_16x16x32_bf16(ah[mi], bh[ni], acc[mi][ni], 0, 0, 0);
                acc[mi][ni] = __builtin_amdgcn_mfma_f32_16x16x32_bf16(ah[mi], bl[ni], acc[mi][ni], 0, 0, 0);
            }
        __syncthreads();
    }
#pragma unroll
    for (int mi = 0; mi < 4; ++mi) {
        int gr0 = row0 + mi * 16 + q * 4;
#pragma unroll
        for (int rr = 0; rr < 4; ++rr) {
            int gr = gr0 + rr;
            if (gr < M) {
#pragma unroll
                for (int ni = 0; ni < 4; ++ni)
                    hbf[(size_t)gr * 256 + wc + ni * 16 + t] = f2bf(acc[mi][ni][rr]);
            }
        }
    }
}

// -------- CSR gather, feature-sliced for XCD-local L2 residency --------
// v3: 8 feature-slices of 32 feats (64B of each hbf row). Slice s is processed
// only by blocks with blockIdx.x%8==s -> (round-robin heuristic) one XCD, whose
// 4MB private L2 holds the 3.2MB column-slice. Beyond-L2 traffic drops from
// ~210MB to ~80MB. Wave = 1 node: 16 edge-slots x 4 feat-lanes (16B each).
// erec loads + output stores are nontemporal to protect slice residency.
__global__ __launch_bounds__(256) void gather_slice(
        const int* __restrict__ row_ptr, const unsigned int* __restrict__ erec,
        const float* __restrict__ dinv,
        const ushort_t* __restrict__ hbf, const float* __restrict__ b,
        ushort_t* __restrict__ outBf) {
    int slice = blockIdx.x & 7;             // -> XCD (heuristic; perf-only)
    int nb = blockIdx.x >> 3;
    int wave = threadIdx.x >> 6;
    int node = nb * 4 + wave;               // N_NODES % 4 == 0
    int lane = threadIdx.x & 63;
    int slot = lane >> 2;                   // 0..15: edge slot
    int fl = lane & 3;                      // 0..3: 16B chunk within 64B slice
    int fbase = slice * 32 + fl * 8;        // this lane's 8 feats
    int beg = row_ptr[node], end = row_ptr[node + 1];
    float dd = dinv[node];
    float acc[8] = {};
    for (int cbeg = beg; cbeg < end; cbeg += 64) {
        int n = end - cbeg; if (n > 64) n = 64;
        unsigned int ev = 0u;
        if (lane < n) ev = __builtin_nontemporal_load(&erec[cbeg + lane]);
        int niter = (n + 15) & ~15;         // pad to x16; pads (ev=0) contribute 0
        for (int k = 0; k < niter; k += 16) {
            unsigned int er = (unsigned int)__shfl((int)ev, k + slot);
            unsigned int s = er & 0xFFFFu;
            float w = bf2f((unsigned short)(er >> 16));
            ushort8 hv = *(const ushort8*)&hbf[(size_t)(s * 256u + (unsigned)fbase)];
#pragma unroll
            for (int j = 0; j < 8; ++j)
                acc[j] = fmaf(bf2f(hv[j]), w, acc[j]);
        }
    }
    // reduce over the 16 edge slots (lane bits 2..5)
#pragma unroll
    for (int j = 0; j < 8; ++j) {
        acc[j] += __shfl_xor(acc[j], 4);
        acc[j] += __shfl_xor(acc[j], 8);
        acc[j] += __shfl_xor(acc[j], 16);
        acc[j] += __shfl_xor(acc[j], 32);
    }
    if (slot == 0) {                        // lanes 0..3 write 4 x 16B = 64B slice
        ushort8 sf = *(const ushort8*)&hbf[(size_t)node * 256 + fbase];
        float4 b0 = *(const float4*)&b[fbase];
        float4 b1 = *(const float4*)&b[fbase + 4];
        float bb[8] = {b0.x, b0.y, b0.z, b0.w, b1.x, b1.y, b1.z, b1.w};
        float ws = dd * dd;
        ushort8 o;
#pragma unroll
        for (int j = 0; j < 8; ++j) {
            float v = fmaxf(fmaf(bf2f(sf[j]), ws, acc[j]) + bb[j], 0.f);
            o[j] = f2bf(v);
        }
        __builtin_nontemporal_store(o, (ushort8*)&outBf[(size_t)node * 256 + fbase]);
    }
}

// ---------------- parallel triple pooling over bf16 h (1 wave/block) ----------------
__global__ __launch_bounds__(64) void pool_partial(
        const ushort_t* __restrict__ h, const int* __restrict__ batch,
        float* __restrict__ psum, int* __restrict__ pmaxi) {
    int g = blockIdx.x;
    int chunk = blockIdx.y;
    int lane = threadIdx.x;  // 64; lane covers feats lane*4..lane*4+3
    int lo = 0, hi = N_NODES;
    while (lo < hi) { int mid = (lo + hi) >> 1; if (batch[mid] < g) lo = mid + 1; else hi = mid; }
    int start = lo;
    lo = 0; hi = N_NODES;
    while (lo < hi) { int mid = (lo + hi) >> 1; if (batch[mid] < g + 1) lo = mid + 1; else hi = mid; }
    int end = lo;
    int len = end - start;
    if (len <= 0) return;
    int per = (len + POOL_CHUNKS - 1) / POOL_CHUNKS;
    int cs = start + chunk * per;
    int ce = cs + per; if (ce > end) ce = end;
    if (cs >= ce) return;
    float4 sum = make_float4(0.f, 0.f, 0.f, 0.f);
    float4 mx  = make_float4(0.f, 0.f, 0.f, 0.f);
    for (int n = cs; n < ce; ++n) {
        ushort4v u = *(const ushort4v*)&h[(size_t)n * 256 + lane * 4];
        float vx = bf2f(u.x), vy = bf2f(u.y), vz = bf2f(u.z), vw = bf2f(u.w);
        sum.x += vx; sum.y += vy; sum.z += vz; sum.w += vw;
        mx.x = fmaxf(mx.x, vx); mx.y = fmaxf(mx.y, vy);
        mx.z = fmaxf(mx.z, vz); mx.w = fmaxf(mx.w, vw);
    }
    float* ps = &psum[g * F + lane * 4];
    atomicAdd(&ps[0], sum.x); atomicAdd(&ps[1], sum.y);
    atomicAdd(&ps[2], sum.z); atomicAdd(&ps[3], sum.w);
    int* pm = &pmaxi[g * F + lane * 4];
    atomicMax(&pm[0], __float_as_int(mx.x)); atomicMax(&pm[1], __float_as_int(mx.y));
    atomicMax(&pm[2], __float_as_int(mx.z)); atomicMax(&pm[3], __float_as_int(mx.w));
}

// ---------------- final GEMM: out[64,128] = [mean|max|sum] @ Wfc + bfc ----------------
__global__ void final_gemm(const float* __restrict__ psum, const int* __restrict__ pmaxi,
                           const int* __restrict__ batch,
                           const float* __restrict__ Wfc, const float* __restrict__ bfc,
                           float* __restrict__ out) {
    int g = blockIdx.x;   // 64
    int o = threadIdx.x;  // 128
    __shared__ float row[G_DIM];
    __shared__ int s_cnt;
    if (threadIdx.x == 0) {
        int lo = 0, hi = N_NODES;
        while (lo < hi) { int mid = (lo + hi) >> 1; if (batch[mid] < g) lo = mid + 1; else hi = mid; }
        int start = lo;
        lo = 0; hi = N_NODES;
        while (lo < hi) { int mid = (lo + hi) >> 1; if (batch[mid] < g + 1) lo = mid + 1; else hi = mid; }
        s_cnt = lo - start;
    }
    __syncthreads();
    float inv = 1.0f / fmaxf((float)s_cnt, 1.0f);
    for (int i = threadIdx.x; i < F; i += 128) {
        float s = psum[g * F + i];
        row[i]       = s * inv;
        row[F + i]   = __int_as_float(pmaxi[g * F + i]);
        row[2*F + i] = s;
    }
    __syncthreads();
    float acc = bfc[o];
    for (int k = 0; k < G_DIM; ++k) acc += row[k] * Wfc[k * F_OUT + o];
    out[g * F_OUT + o] = acc;
}

extern "C" void kernel_launch(void* const* d_in, const int* in_sizes, int n_in,
                              void* d_out, int out_size, void* d_ws, size_t ws_size,
                              hipStream_t stream) {
    const float* x    = (const float*)d_in[0];
    const int*   ei   = (const int*)d_in[1];
    const int*   batch= (const int*)d_in[2];
    const float* W1   = (const float*)d_in[4];
    const float* b1   = (const float*)d_in[5];
    const float* W2   = (const float*)d_in[6];
    const float* b2   = (const float*)d_in[7];
    const float* Wfc  = (const float*)d_in[8];
    const float* bfc  = (const float*)d_in[9];
    float* out = (float*)d_out;

    const int* src = ei;
    const int* dst = ei + N_EDGES;

    const size_t NF = (size_t)N_NODES * F;   // 12.8M

    ushort_t* hbf  = (ushort_t*)d_ws;        // [N,256] bf16 gemm out (25.6 MB)
    ushort_t* h1bf = hbf + NF;               // [N,256] bf16 gather1 out; reused as h2bf
    ushort_t* h2bf = h1bf;                   //   (h1 consumed by gemm2 before gather2 writes)
    short* w1hi  = (short*)(h1bf + NF);      // 4x 64K shorts
    short* w1lo  = w1hi + 65536;
    short* w2hi  = w1lo + 65536;
    short* w2lo  = w2hi + 65536;
    float* dinv  = (float*)(w2lo + 65536);   // [N]
    // ---- contiguous zero-init region: deg, cursor, psum, pmaxi ----
    int*   deg   = (int*)(dinv + N_NODES);   // [N]
    int*   cursor= deg + N_NODES;            // [N]
    float* psum  = (float*)(cursor + N_NODES);   // [64][256]
    int*   pmaxi = (int*)(psum + N_GRAPHS * F);  // [64][256]
    // ---- rest ----
    int*   row_ptr = pmaxi + N_GRAPHS * F;   // [N+1]
    int*   btot  = row_ptr + N_NODES + 1;    // [256]
    unsigned int* erec = (unsigned int*)(btot + 256);   // [E] 4B records (3.2 MB)

    // ---- degree + norm + CSR (+ W casts fused); ONE memset for all zeroed buffers ----
    hipMemsetAsync(deg, 0, (2 * N_NODES + 2 * N_GRAPHS * F) * sizeof(int), stream);
    prep_w_deg<<<512 + (N_EDGES + 255) / 256, 256, 0, stream>>>(
        W1, W2, w1hi, w1lo, w2hi, w2lo, dst, deg);
    scan_blocks<<<SCAN_NB, 256, 0, stream>>>(deg, row_ptr, btot, dinv);
    add_offsets<<<SCAN_NB, 256, 0, stream>>>(row_ptr, btot);
    bucket_edges<<<(N_EDGES + 255) / 256, 256, 0, stream>>>(src, dst, dinv, row_ptr,
                                                            cursor, erec);

    int ggemm = (N_NODES + BM - 1) / BM;      // 782
    int ngb = N_NODES / 4;                    // 12500 node-blocks
    int ngs = 8 * ngb;                        // x8 feature slices = 100000 blocks

    // ---- layer 1 ----
    gemm_mfma<<<ggemm, 256, 0, stream>>>(x, w1hi, w1lo, hbf, N_NODES);
    gather_slice<<<ngs, 256, 0, stream>>>(row_ptr, erec, dinv, hbf, b1, h1bf);

    // ---- layer 2 ----
    gemm_mfma_bf16<<<ggemm, 256, 0, stream>>>(h1bf, w2hi, w2lo, hbf, N_NODES);
    gather_slice<<<ngs, 256, 0, stream>>>(row_ptr, erec, dinv, hbf, b2, h2bf);

    // ---- pooling + classifier ----
    pool_partial<<<dim3(N_GRAPHS, POOL_CHUNKS), 64, 0, stream>>>(h2bf, batch, psum, pmaxi);
    final_gemm<<<N_GRAPHS, F_OUT, 0, stream>>>(psum, pmaxi, batch, Wfc, bfc, out);
}

// Round 6
// 356.078 us; speedup vs baseline: 1.7149x; 1.7149x over previous
//
#include <hip/hip_runtime.h>

#define N_NODES 50000
#define N_EDGES 800000
#define N_GRAPHS 64
#define F 256        // F_IN == F_HID
#define F_OUT 128
#define G_DIM 768    // 3*F
#define SCAN_NB ((N_NODES + 255) / 256)   // 196
#define POOL_CHUNKS 32

typedef unsigned short ushort_t;
typedef short short8 __attribute__((ext_vector_type(8)));
typedef unsigned short ushort8 __attribute__((ext_vector_type(8)));
typedef unsigned short ushort4v __attribute__((ext_vector_type(4)));
typedef float float4v __attribute__((ext_vector_type(4)));
typedef float f32x2 __attribute__((ext_vector_type(2)));
typedef unsigned int uint4v __attribute__((ext_vector_type(4)));

// ---- bf16 helpers (RNE) ----
__device__ __forceinline__ unsigned short f2bf(float f) {
    unsigned int u = __float_as_uint(f);
    u += 0x7FFFu + ((u >> 16) & 1u);
    return (unsigned short)(u >> 16);
}
__device__ __forceinline__ float bf2f(unsigned short s) {
    return __uint_as_float(((unsigned int)s) << 16);
}

// ---- fp8 e4m3 encode/decode: HW cvt when available, exact bit-trick fallback ----
__device__ __forceinline__ unsigned char fp8_enc(float v) {
#if __has_builtin(__builtin_amdgcn_cvt_pk_fp8_f32)
    return (unsigned char)__builtin_amdgcn_cvt_pk_fp8_f32(v, v, 0, false);
#else
    float x = v * 0x1p-120f;                    // align e4m3 to f32 bits 27..20
    unsigned int u = __float_as_uint(x);
    unsigned int mag = u & 0x7FFFFFFFu;
    unsigned int r = mag + 0x0007FFFFu + ((mag >> 20) & 1u);   // RNE at bit 20
    unsigned int em = r >> 20;
    if (em > 0x7Eu) em = 0x7Eu;                 // clamp to +-448, no NaN
    return (unsigned char)(em | ((u >> 24) & 0x80u));
#endif
}

// decode 4 fp8 (one u32) -> 4 floats
__device__ __forceinline__ void fp8x4_dec(unsigned int u, float* o) {
#if __has_builtin(__builtin_amdgcn_cvt_pk_f32_fp8)
    f32x2 d0 = __builtin_amdgcn_cvt_pk_f32_fp8((int)u, false);
    f32x2 d1 = __builtin_amdgcn_cvt_pk_f32_fp8((int)u, true);
    o[0] = d0[0]; o[1] = d0[1]; o[2] = d1[0]; o[3] = d1[1];
#else
#pragma unroll
    for (int i = 0; i < 4; ++i) {
        unsigned int b = (u >> (8 * i)) & 0xFFu;
        unsigned int bits = ((b & 0x7Fu) << 20) | ((b & 0x80u) << 24);
        o[i] = __uint_as_float(bits) * 0x1p+120f;   // exact incl. subnormals
    }
#endif
}

// ---- async global->LDS, 16B per lane; LDS dest = wave-uniform base + lane*16 ----
__device__ __forceinline__ void gld_lds16(const void* gsrc, void* ldst) {
    __builtin_amdgcn_global_load_lds(
        (const __attribute__((address_space(1))) unsigned int*)gsrc,
        (__attribute__((address_space(3))) unsigned int*)ldst, 16, 0, 0);
}

// ---------------- fused: W1/W2 transposed hi/lo cast (blocks 0..511) + degree count ----------------
__global__ void prep_w_deg(const float* __restrict__ W1, const float* __restrict__ W2,
                           short* __restrict__ hi1, short* __restrict__ lo1,
                           short* __restrict__ hi2, short* __restrict__ lo2,
                           const int* __restrict__ dst, int* __restrict__ deg) {
    int blk = blockIdx.x;
    if (blk < 512) {
        const float* W = (blk < 256) ? W1 : W2;
        short* hi = (blk < 256) ? hi1 : hi2;
        short* lo = (blk < 256) ? lo1 : lo2;
        int n = blk & 255;
        int k = threadIdx.x;
        float v = W[k * 256 + n];
        unsigned short h = f2bf(v);
        hi[n * 256 + k] = (short)h;
        lo[n * 256 + k] = (short)f2bf(v - bf2f(h));
    } else {
        int e = (blk - 512) * 256 + threadIdx.x;
        if (e < N_EDGES) atomicAdd(&deg[dst[e]], 1);
    }
}

// ---------------- scan blocks + fused dinv (btot holds RAW per-block sums) ----------------
__global__ void scan_blocks(const int* __restrict__ deg, int* __restrict__ row_ptr,
                            int* __restrict__ block_tot, float* __restrict__ dinv) {
    __shared__ int sd[256];
    int t = threadIdx.x;
    int idx = blockIdx.x * 256 + t;
    int v = (idx < N_NODES) ? deg[idx] : 0;
    if (idx < N_NODES) dinv[idx] = rsqrtf((float)(v + 1));   // +1 self-loop
    sd[t] = v;
    __syncthreads();
    for (int off = 1; off < 256; off <<= 1) {
        int a = (t >= off) ? sd[t - off] : 0;
        __syncthreads();
        sd[t] += a;
        __syncthreads();
    }
    if (idx < N_NODES) row_ptr[idx] = sd[t] - v;
    if (t == 255) block_tot[blockIdx.x] = sd[255];
}

// ---------------- add block offsets; each block reduces btot[0..blk) itself ----------------
__global__ void add_offsets(int* __restrict__ row_ptr, const int* __restrict__ block_tot) {
    __shared__ int sd[256];
    int t = threadIdx.x;
    int blk = blockIdx.x;
    sd[t] = (t < blk && t < SCAN_NB) ? block_tot[t] : 0;
    __syncthreads();
    for (int off = 128; off > 0; off >>= 1) {
        if (t < off) sd[t] += sd[t + off];
        __syncthreads();
    }
    int base = sd[0];
    int idx = blk * 256 + t;
    if (idx < N_NODES) row_ptr[idx] += base;
    if (idx == 0) row_ptr[N_NODES] = N_EDGES;
}

// ---------------- bucket edges into CSR order; packed 4B record ----------------
// erec[pos] = src (low 16) | bf16(norm) (high 16)
__global__ void bucket_edges(const int* __restrict__ src, const int* __restrict__ dst,
                             const float* __restrict__ dinv,
                             const int* __restrict__ row_ptr, int* __restrict__ cursor,
                             unsigned int* __restrict__ erec) {
    int e = blockIdx.x * blockDim.x + threadIdx.x;
    if (e < N_EDGES) {
        int d = dst[e];
        int s = src[e];
        int pos = row_ptr[d] + atomicAdd(&cursor[d], 1);
        unsigned int w = (unsigned int)f2bf(dinv[s] * dinv[d]);
        erec[pos] = (unsigned int)s | (w << 16);
    }
}

// ---------------- GEMM1: split-bf16 MFMA, fp32 A, A-prefetch pipeline; fp8 out ----------------
#define BM 64
#define BK 32
__global__ __launch_bounds__(256) void gemm_mfma(
        const float* __restrict__ A,
        const short* __restrict__ Bthi, const short* __restrict__ Btlo,
        unsigned char* __restrict__ h8, int M) {
    __shared__ short sAh[BM * BK], sAl[BM * BK];       // 4KB + 4KB
    __shared__ short sBh[256 * BK], sBl[256 * BK];     // 16KB + 16KB
    int tid = threadIdx.x;
    int wave = tid >> 6, lane = tid & 63;
    int q = lane >> 4, t = lane & 15;
    int row0 = blockIdx.x * BM;
    int wc = wave * 64;            // wave's 64-col slice of N=256

    int lrow = lane >> 2;          // 0..15 (B staging)
    int lk = (lane & 3) * 8;       // k offset (shorts)
    int ar = tid >> 2;             // A staging: row 0..63
    int ak = (tid & 3) * 8;        // A staging: 8 floats at kt+ak

    int ga = row0 + ar; if (ga >= M) ga = M - 1;       // clamp; never stored
    const float* abase = &A[(size_t)ga * 256 + ak];
    float4 a0 = *(const float4*)(abase);
    float4 a1 = *(const float4*)(abase + 4);

    float4v acc[4][4] = {};
    for (int kt = 0; kt < 256; kt += BK) {
#pragma unroll
        for (int j = 0; j < 4; ++j) {
            int n = wave * 64 + j * 16 + lrow;
            size_t boff = (size_t)n * 256 + kt + lk;
            int ldso = wave * 2048 + j * 512 + lane * 8;
            gld_lds16(&Bthi[boff], &sBh[ldso]);
            gld_lds16(&Btlo[boff], &sBl[ldso]);
        }
        {
            short8 h, l;
            unsigned short hh;
            hh = f2bf(a0.x); h[0] = (short)hh; l[0] = (short)f2bf(a0.x - bf2f(hh));
            hh = f2bf(a0.y); h[1] = (short)hh; l[1] = (short)f2bf(a0.y - bf2f(hh));
            hh = f2bf(a0.z); h[2] = (short)hh; l[2] = (short)f2bf(a0.z - bf2f(hh));
            hh = f2bf(a0.w); h[3] = (short)hh; l[3] = (short)f2bf(a0.w - bf2f(hh));
            hh = f2bf(a1.x); h[4] = (short)hh; l[4] = (short)f2bf(a1.x - bf2f(hh));
            hh = f2bf(a1.y); h[5] = (short)hh; l[5] = (short)f2bf(a1.y - bf2f(hh));
            hh = f2bf(a1.z); h[6] = (short)hh; l[6] = (short)f2bf(a1.z - bf2f(hh));
            hh = f2bf(a1.w); h[7] = (short)hh; l[7] = (short)f2bf(a1.w - bf2f(hh));
            *(short8*)&sAh[ar * BK + ak] = h;
            *(short8*)&sAl[ar * BK + ak] = l;
        }
        float4 na0 = a0, na1 = a1;
        if (kt + BK < 256) {
            na0 = *(const float4*)(abase + kt + BK);
            na1 = *(const float4*)(abase + kt + BK + 4);
        }
        __syncthreads();
        short8 ah[4], al[4], bh[4], bl[4];
#pragma unroll
        for (int mi = 0; mi < 4; ++mi) {
            int r = mi * 16 + t;
            ah[mi] = *(const short8*)&sAh[r * BK + q * 8];
            al[mi] = *(const short8*)&sAl[r * BK + q * 8];
        }
#pragma unroll
        for (int ni = 0; ni < 4; ++ni) {
            int n = wc + ni * 16 + t;
            bh[ni] = *(const short8*)&sBh[n * BK + q * 8];
            bl[ni] = *(const short8*)&sBl[n * BK + q * 8];
        }
#pragma unroll
        for (int mi = 0; mi < 4; ++mi)
#pragma unroll
            for (int ni = 0; ni < 4; ++ni) {
                acc[mi][ni] = __builtin_amdgcn_mfma_f32_16x16x32_bf16(ah[mi], bh[ni], acc[mi][ni], 0, 0, 0);
                acc[mi][ni] = __builtin_amdgcn_mfma_f32_16x16x32_bf16(ah[mi], bl[ni], acc[mi][ni], 0, 0, 0);
                acc[mi][ni] = __builtin_amdgcn_mfma_f32_16x16x32_bf16(al[mi], bh[ni], acc[mi][ni], 0, 0, 0);
            }
        __syncthreads();
        a0 = na0; a1 = na1;
    }
#pragma unroll
    for (int mi = 0; mi < 4; ++mi) {
        int gr0 = row0 + mi * 16 + q * 4;
#pragma unroll
        for (int rr = 0; rr < 4; ++rr) {
            int gr = gr0 + rr;
            if (gr < M) {
#pragma unroll
                for (int ni = 0; ni < 4; ++ni)
                    h8[(size_t)gr * 256 + wc + ni * 16 + t] = fp8_enc(acc[mi][ni][rr]);
            }
        }
    }
}

// ---------------- GEMM2: bf16 A fully preloaded to regs; 2 MFMAs; fp8 out ----------------
__global__ __launch_bounds__(256) void gemm_mfma_bf16(
        const ushort_t* __restrict__ A,   // [M,256] bf16
        const short* __restrict__ Bthi, const short* __restrict__ Btlo,
        unsigned char* __restrict__ h8, int M) {
    __shared__ short sA[BM * BK];                      // 4KB
    __shared__ short sBh[256 * BK], sBl[256 * BK];     // 16KB + 16KB
    int tid = threadIdx.x;
    int wave = tid >> 6, lane = tid & 63;
    int q = lane >> 4, t = lane & 15;
    int row0 = blockIdx.x * BM;
    int wc = wave * 64;

    int lrow = lane >> 2;          // 0..15 (B staging)
    int lk = (lane & 3) * 8;       // k offset (shorts)
    int ar = tid >> 2;             // A staging: row 0..63
    int ak = (tid & 3) * 8;        // 8 shorts at kt+ak

    int ga = row0 + ar; if (ga >= M) ga = M - 1;
    const ushort_t* abase = &A[(size_t)ga * 256 + ak];
    ushort8 areg[8];
#pragma unroll
    for (int i = 0; i < 8; ++i) areg[i] = *(const ushort8*)(abase + i * BK);

    float4v acc[4][4] = {};
#pragma unroll
    for (int ki = 0; ki < 8; ++ki) {
        int kt = ki * BK;
#pragma unroll
        for (int j = 0; j < 4; ++j) {
            int n = wave * 64 + j * 16 + lrow;
            size_t boff = (size_t)n * 256 + kt + lk;
            int ldso = wave * 2048 + j * 512 + lane * 8;
            gld_lds16(&Bthi[boff], &sBh[ldso]);
            gld_lds16(&Btlo[boff], &sBl[ldso]);
        }
        *(ushort8*)&sA[ar * BK + ak] = areg[ki];
        __syncthreads();
        short8 ah[4], bh[4], bl[4];
#pragma unroll
        for (int mi = 0; mi < 4; ++mi) {
            int r = mi * 16 + t;
            ah[mi] = *(const short8*)&sA[r * BK + q * 8];
        }
#pragma unroll
        for (int ni = 0; ni < 4; ++ni) {
            int n = wc + ni * 16 + t;
            bh[ni] = *(const short8*)&sBh[n * BK + q * 8];
            bl[ni] = *(const short8*)&sBl[n * BK + q * 8];
        }
#pragma unroll
        for (int mi = 0; mi < 4; ++mi)
#pragma unroll
            for (int ni = 0; ni < 4; ++ni) {
                acc[mi][ni] = __builtin_amdgcn_mfma_f32_16x16x32_bf16(ah[mi], bh[ni], acc[mi][ni], 0, 0, 0);
                acc[mi][ni] = __builtin_amdgcn_mfma_f32_16x16x32_bf16(ah[mi], bl[ni], acc[mi][ni], 0, 0, 0);
            }
        __syncthreads();
    }
#pragma unroll
    for (int mi = 0; mi < 4; ++mi) {
        int gr0 = row0 + mi * 16 + q * 4;
#pragma unroll
        for (int rr = 0; rr < 4; ++rr) {
            int gr = gr0 + rr;
            if (gr < M) {
#pragma unroll
                for (int ni = 0; ni < 4; ++ni)
                    h8[(size_t)gr * 256 + wc + ni * 16 + t] = fp8_enc(acc[mi][ni][rr]);
            }
        }
    }
}

// -------- CSR gather over fp8 h; 4 groups x 16 lanes x 16 feats (16B), 4 edges in flight --------
// Pads (ev=0) read row 0 with w=0: harmless. h8 loads are CACHED (L2-resident is the point);
// erec loads and output stores are nontemporal (streaming).
__global__ __launch_bounds__(256) void gather_fp8(
        const int* __restrict__ row_ptr, const unsigned int* __restrict__ erec,
        const float* __restrict__ dinv,
        const unsigned char* __restrict__ h8, const float* __restrict__ b,
        ushort_t* __restrict__ outBf) {
    int wave = threadIdx.x >> 6;
    int node = blockIdx.x * 4 + wave;      // N_NODES % 4 == 0
    int lane = threadIdx.x & 63;
    int g = lane >> 4;                      // 4 edge groups
    int hl = lane & 15;                     // feats hl*16 .. +15 (16 fp8 = 16B)
    int beg = row_ptr[node], end = row_ptr[node + 1];
    float dd = dinv[node];
    float acc[16] = {};
    for (int cbeg = beg; cbeg < end; cbeg += 64) {
        int n = end - cbeg; if (n > 64) n = 64;
        unsigned int ev = 0u;
        if (lane < n) ev = __builtin_nontemporal_load(&erec[cbeg + lane]);
        int niter = (n + 15) & ~15;         // pad to x16; pads contribute 0
        for (int k = 0; k < niter; k += 16) {
            unsigned int er0 = (unsigned int)__shfl((int)ev, k + g);
            unsigned int er1 = (unsigned int)__shfl((int)ev, k + 4 + g);
            unsigned int er2 = (unsigned int)__shfl((int)ev, k + 8 + g);
            unsigned int er3 = (unsigned int)__shfl((int)ev, k + 12 + g);
            uint4v p0 = *(const uint4v*)&h8[(size_t)((er0 & 0xFFFFu) * 256u + (unsigned)hl * 16u)];
            uint4v p1 = *(const uint4v*)&h8[(size_t)((er1 & 0xFFFFu) * 256u + (unsigned)hl * 16u)];
            uint4v p2 = *(const uint4v*)&h8[(size_t)((er2 & 0xFFFFu) * 256u + (unsigned)hl * 16u)];
            uint4v p3 = *(const uint4v*)&h8[(size_t)((er3 & 0xFFFFu) * 256u + (unsigned)hl * 16u)];
            float w0 = bf2f((unsigned short)(er0 >> 16));
            float w1 = bf2f((unsigned short)(er1 >> 16));
            float w2 = bf2f((unsigned short)(er2 >> 16));
            float w3 = bf2f((unsigned short)(er3 >> 16));
            float d0[4], d1[4], d2[4], d3[4];
#pragma unroll
            for (int wdi = 0; wdi < 4; ++wdi) {
                fp8x4_dec(p0[wdi], d0);
                fp8x4_dec(p1[wdi], d1);
                fp8x4_dec(p2[wdi], d2);
                fp8x4_dec(p3[wdi], d3);
#pragma unroll
                for (int j = 0; j < 4; ++j) {
                    int a = wdi * 4 + j;
                    acc[a] = fmaf(d0[j], w0, acc[a]);
                    acc[a] = fmaf(d1[j], w1, acc[a]);
                    acc[a] = fmaf(d2[j], w2, acc[a]);
                    acc[a] = fmaf(d3[j], w3, acc[a]);
                }
            }
        }
    }
#pragma unroll
    for (int j = 0; j < 16; ++j) {
        acc[j] += __shfl_xor(acc[j], 16);
        acc[j] += __shfl_xor(acc[j], 32);
    }
    if (g == 0) {
        uint4v sp = *(const uint4v*)&h8[(size_t)node * 256 + hl * 16];
        float sf[16];
        fp8x4_dec(sp[0], &sf[0]);
        fp8x4_dec(sp[1], &sf[4]);
        fp8x4_dec(sp[2], &sf[8]);
        fp8x4_dec(sp[3], &sf[12]);
        float4 b0 = *(const float4*)&b[hl * 16];
        float4 b1 = *(const float4*)&b[hl * 16 + 4];
        float4 b2 = *(const float4*)&b[hl * 16 + 8];
        float4 b3 = *(const float4*)&b[hl * 16 + 12];
        float bb[16] = {b0.x, b0.y, b0.z, b0.w, b1.x, b1.y, b1.z, b1.w,
                        b2.x, b2.y, b2.z, b2.w, b3.x, b3.y, b3.z, b3.w};
        float ws = dd * dd;
        ushort8 o0, o1;
#pragma unroll
        for (int j = 0; j < 8; ++j) {
            float v0 = fmaxf(fmaf(sf[j], ws, acc[j]) + bb[j], 0.f);
            o0[j] = f2bf(v0);
            float v1 = fmaxf(fmaf(sf[8 + j], ws, acc[8 + j]) + bb[8 + j], 0.f);
            o1[j] = f2bf(v1);
        }
        __builtin_nontemporal_store(o0, (ushort8*)&outBf[(size_t)node * 256 + hl * 16]);
        __builtin_nontemporal_store(o1, (ushort8*)&outBf[(size_t)node * 256 + hl * 16 + 8]);
    }
}

// ---------------- parallel triple pooling over bf16 h (1 wave/block) ----------------
__global__ __launch_bounds__(64) void pool_partial(
        const ushort_t* __restrict__ h, const int* __restrict__ batch,
        float* __restrict__ psum, int* __restrict__ pmaxi) {
    int g = blockIdx.x;
    int chunk = blockIdx.y;
    int lane = threadIdx.x;  // 64; lane covers feats lane*4..lane*4+3
    int lo = 0, hi = N_NODES;
    while (lo < hi) { int mid = (lo + hi) >> 1; if (batch[mid] < g) lo = mid + 1; else hi = mid; }
    int start = lo;
    lo = 0; hi = N_NODES;
    while (lo < hi) { int mid = (lo + hi) >> 1; if (batch[mid] < g + 1) lo = mid + 1; else hi = mid; }
    int end = lo;
    int len = end - start;
    if (len <= 0) return;
    int per = (len + POOL_CHUNKS - 1) / POOL_CHUNKS;
    int cs = start + chunk * per;
    int ce = cs + per; if (ce > end) ce = end;
    if (cs >= ce) return;
    float4 sum = make_float4(0.f, 0.f, 0.f, 0.f);
    float4 mx  = make_float4(0.f, 0.f, 0.f, 0.f);
    for (int n = cs; n < ce; ++n) {
        ushort4v u = *(const ushort4v*)&h[(size_t)n * 256 + lane * 4];
        float vx = bf2f(u.x), vy = bf2f(u.y), vz = bf2f(u.z), vw = bf2f(u.w);
        sum.x += vx; sum.y += vy; sum.z += vz; sum.w += vw;
        mx.x = fmaxf(mx.x, vx); mx.y = fmaxf(mx.y, vy);
        mx.z = fmaxf(mx.z, vz); mx.w = fmaxf(mx.w, vw);
    }
    float* ps = &psum[g * F + lane * 4];
    atomicAdd(&ps[0], sum.x); atomicAdd(&ps[1], sum.y);
    atomicAdd(&ps[2], sum.z); atomicAdd(&ps[3], sum.w);
    int* pm = &pmaxi[g * F + lane * 4];
    atomicMax(&pm[0], __float_as_int(mx.x)); atomicMax(&pm[1], __float_as_int(mx.y));
    atomicMax(&pm[2], __float_as_int(mx.z)); atomicMax(&pm[3], __float_as_int(mx.w));
}

// ---------------- final GEMM: out[64,128] = [mean|max|sum] @ Wfc + bfc ----------------
__global__ void final_gemm(const float* __restrict__ psum, const int* __restrict__ pmaxi,
                           const int* __restrict__ batch,
                           const float* __restrict__ Wfc, const float* __restrict__ bfc,
                           float* __restrict__ out) {
    int g = blockIdx.x;   // 64
    int o = threadIdx.x;  // 128
    __shared__ float row[G_DIM];
    __shared__ int s_cnt;
    if (threadIdx.x == 0) {
        int lo = 0, hi = N_NODES;
        while (lo < hi) { int mid = (lo + hi) >> 1; if (batch[mid] < g) lo = mid + 1; else hi = mid; }
        int start = lo;
        lo = 0; hi = N_NODES;
        while (lo < hi) { int mid = (lo + hi) >> 1; if (batch[mid] < g + 1) lo = mid + 1; else hi = mid; }
        s_cnt = lo - start;
    }
    __syncthreads();
    float inv = 1.0f / fmaxf((float)s_cnt, 1.0f);
    for (int i = threadIdx.x; i < F; i += 128) {
        float s = psum[g * F + i];
        row[i]       = s * inv;
        row[F + i]   = __int_as_float(pmaxi[g * F + i]);
        row[2*F + i] = s;
    }
    __syncthreads();
    float acc = bfc[o];
    for (int k = 0; k < G_DIM; ++k) acc += row[k] * Wfc[k * F_OUT + o];
    out[g * F_OUT + o] = acc;
}

extern "C" void kernel_launch(void* const* d_in, const int* in_sizes, int n_in,
                              void* d_out, int out_size, void* d_ws, size_t ws_size,
                              hipStream_t stream) {
    const float* x    = (const float*)d_in[0];
    const int*   ei   = (const int*)d_in[1];
    const int*   batch= (const int*)d_in[2];
    const float* W1   = (const float*)d_in[4];
    const float* b1   = (const float*)d_in[5];
    const float* W2   = (const float*)d_in[6];
    const float* b2   = (const float*)d_in[7];
    const float* Wfc  = (const float*)d_in[8];
    const float* bfc  = (const float*)d_in[9];
    float* out = (float*)d_out;

    const int* src = ei;
    const int* dst = ei + N_EDGES;

    const size_t NF = (size_t)N_NODES * F;   // 12.8M

    unsigned char* h8 = (unsigned char*)d_ws;   // [N,256] fp8 gemm out (12.8 MB)
    ushort_t* h1bf = (ushort_t*)(h8 + NF);      // [N,256] bf16 gather1 out; reused as h2bf
    ushort_t* h2bf = h1bf;                      //   (h1 consumed by gemm2 before gather2 writes)
    short* w1hi  = (short*)(h1bf + NF);         // 4x 64K shorts
    short* w1lo  = w1hi + 65536;
    short* w2hi  = w1lo + 65536;
    short* w2lo  = w2hi + 65536;
    float* dinv  = (float*)(w2lo + 65536);   // [N]
    // ---- contiguous zero-init region: deg, cursor, psum, pmaxi ----
    int*   deg   = (int*)(dinv + N_NODES);   // [N]
    int*   cursor= deg + N_NODES;            // [N]
    float* psum  = (float*)(cursor + N_NODES);   // [64][256]
    int*   pmaxi = (int*)(psum + N_GRAPHS * F);  // [64][256]
    // ---- rest ----
    int*   row_ptr = pmaxi + N_GRAPHS * F;   // [N+1]
    int*   btot  = row_ptr + N_NODES + 1;    // [256]
    unsigned int* erec = (unsigned int*)(btot + 256);   // [E] 4B records (3.2 MB)

    // ---- degree + norm + CSR (+ W casts fused); ONE memset for all zeroed buffers ----
    hipMemsetAsync(deg, 0, (2 * N_NODES + 2 * N_GRAPHS * F) * sizeof(int), stream);
    prep_w_deg<<<512 + (N_EDGES + 255) / 256, 256, 0, stream>>>(
        W1, W2, w1hi, w1lo, w2hi, w2lo, dst, deg);
    scan_blocks<<<SCAN_NB, 256, 0, stream>>>(deg, row_ptr, btot, dinv);
    add_offsets<<<SCAN_NB, 256, 0, stream>>>(row_ptr, btot);
    bucket_edges<<<(N_EDGES + 255) / 256, 256, 0, stream>>>(src, dst, dinv, row_ptr,
                                                            cursor, erec);

    int ggemm = (N_NODES + BM - 1) / BM;      // 782
    int ngb = N_NODES / 4;                    // 12500 blocks of 4 waves

    // ---- layer 1 ----
    gemm_mfma<<<ggemm, 256, 0, stream>>>(x, w1hi, w1lo, h8, N_NODES);
    gather_fp8<<<ngb, 256, 0, stream>>>(row_ptr, erec, dinv, h8, b1, h1bf);

    // ---- layer 2 ----
    gemm_mfma_bf16<<<ggemm, 256, 0, stream>>>(h1bf, w2hi, w2lo, h8, N_NODES);
    gather_fp8<<<ngb, 256, 0, stream>>>(row_ptr, erec, dinv, h8, b2, h2bf);

    // ---- pooling + classifier ----
    pool_partial<<<dim3(N_GRAPHS, POOL_CHUNKS), 64, 0, stream>>>(h2bf, batch, psum, pmaxi);
    final_gemm<<<N_GRAPHS, F_OUT, 0, stream>>>(psum, pmaxi, batch, Wfc, bfc, out);
}

// Round 7
// 350.102 us; speedup vs baseline: 1.7442x; 1.0171x over previous
//
#include <hip/hip_runtime.h>

#define N_NODES 50000
#define N_EDGES 800000
#define N_GRAPHS 64
#define F 256        // F_IN == F_HID
#define F_OUT 128
#define G_DIM 768    // 3*F
#define SCAN_NB ((N_NODES + 255) / 256)   // 196
#define POOL_CHUNKS 32
#define EBLK ((N_EDGES + 255) / 256)      // 3125

typedef unsigned short ushort_t;
typedef short short8 __attribute__((ext_vector_type(8)));
typedef unsigned short ushort8 __attribute__((ext_vector_type(8)));
typedef unsigned short ushort4v __attribute__((ext_vector_type(4)));
typedef float float4v __attribute__((ext_vector_type(4)));
typedef float f32x2 __attribute__((ext_vector_type(2)));
typedef unsigned int uint4v __attribute__((ext_vector_type(4)));

// ---- bf16 helpers (RNE) ----
__device__ __forceinline__ unsigned short f2bf(float f) {
    unsigned int u = __float_as_uint(f);
    u += 0x7FFFu + ((u >> 16) & 1u);
    return (unsigned short)(u >> 16);
}
__device__ __forceinline__ float bf2f(unsigned short s) {
    return __uint_as_float(((unsigned int)s) << 16);
}

// ---- fp8 e4m3 encode/decode: HW cvt when available, exact bit-trick fallback ----
__device__ __forceinline__ unsigned char fp8_enc(float v) {
#if __has_builtin(__builtin_amdgcn_cvt_pk_fp8_f32)
    return (unsigned char)__builtin_amdgcn_cvt_pk_fp8_f32(v, v, 0, false);
#else
    float x = v * 0x1p-120f;                    // align e4m3 to f32 bits 27..20
    unsigned int u = __float_as_uint(x);
    unsigned int mag = u & 0x7FFFFFFFu;
    unsigned int r = mag + 0x0007FFFFu + ((mag >> 20) & 1u);   // RNE at bit 20
    unsigned int em = r >> 20;
    if (em > 0x7Eu) em = 0x7Eu;                 // clamp to +-448, no NaN
    return (unsigned char)(em | ((u >> 24) & 0x80u));
#endif
}

// decode 4 fp8 (one u32) -> 4 floats
__device__ __forceinline__ void fp8x4_dec(unsigned int u, float* o) {
#if __has_builtin(__builtin_amdgcn_cvt_pk_f32_fp8)
    f32x2 d0 = __builtin_amdgcn_cvt_pk_f32_fp8((int)u, false);
    f32x2 d1 = __builtin_amdgcn_cvt_pk_f32_fp8((int)u, true);
    o[0] = d0[0]; o[1] = d0[1]; o[2] = d1[0]; o[3] = d1[1];
#else
#pragma unroll
    for (int i = 0; i < 4; ++i) {
        unsigned int b = (u >> (8 * i)) & 0xFFu;
        unsigned int bits = ((b & 0x7Fu) << 20) | ((b & 0x80u) << 24);
        o[i] = __uint_as_float(bits) * 0x1p+120f;   // exact incl. subnormals
    }
#endif
}

// ---- async global->LDS, 16B per lane; LDS dest = wave-uniform base + lane*16 ----
__device__ __forceinline__ void gld_lds16(const void* gsrc, void* ldst) {
    __builtin_amdgcn_global_load_lds(
        (const __attribute__((address_space(1))) unsigned int*)gsrc,
        (__attribute__((address_space(3))) unsigned int*)ldst, 16, 0, 0);
}

// ---------------- fused: W1/W2 transposed hi/lo cast (blocks 0..511) + degree count ----------------
__global__ void prep_w_deg(const float* __restrict__ W1, const float* __restrict__ W2,
                           short* __restrict__ hi1, short* __restrict__ lo1,
                           short* __restrict__ hi2, short* __restrict__ lo2,
                           const int* __restrict__ dst, int* __restrict__ deg) {
    int blk = blockIdx.x;
    if (blk < 512) {
        const float* W = (blk < 256) ? W1 : W2;
        short* hi = (blk < 256) ? hi1 : hi2;
        short* lo = (blk < 256) ? lo1 : lo2;
        int n = blk & 255;
        int k = threadIdx.x;
        float v = W[k * 256 + n];
        unsigned short h = f2bf(v);
        hi[n * 256 + k] = (short)h;
        lo[n * 256 + k] = (short)f2bf(v - bf2f(h));
    } else {
        int e = (blk - 512) * 256 + threadIdx.x;
        if (e < N_EDGES) atomicAdd(&deg[dst[e]], 1);
    }
}

// ---------------- scan blocks + fused dinv (btot holds RAW per-block sums) ----------------
__global__ void scan_blocks(const int* __restrict__ deg, int* __restrict__ row_ptr,
                            int* __restrict__ block_tot, float* __restrict__ dinv) {
    __shared__ int sd[256];
    int t = threadIdx.x;
    int idx = blockIdx.x * 256 + t;
    int v = (idx < N_NODES) ? deg[idx] : 0;
    if (idx < N_NODES) dinv[idx] = rsqrtf((float)(v + 1));   // +1 self-loop
    sd[t] = v;
    __syncthreads();
    for (int off = 1; off < 256; off <<= 1) {
        int a = (t >= off) ? sd[t - off] : 0;
        __syncthreads();
        sd[t] += a;
        __syncthreads();
    }
    if (idx < N_NODES) row_ptr[idx] = sd[t] - v;
    if (t == 255) block_tot[blockIdx.x] = sd[255];
}

// ---------------- add block offsets; each block reduces btot[0..blk) itself ----------------
__global__ void add_offsets(int* __restrict__ row_ptr, const int* __restrict__ block_tot) {
    __shared__ int sd[256];
    int t = threadIdx.x;
    int blk = blockIdx.x;
    sd[t] = (t < blk && t < SCAN_NB) ? block_tot[t] : 0;
    __syncthreads();
    for (int off = 128; off > 0; off >>= 1) {
        if (t < off) sd[t] += sd[t + off];
        __syncthreads();
    }
    int base = sd[0];
    int idx = blk * 256 + t;
    if (idx < N_NODES) row_ptr[idx] += base;
    if (idx == 0) row_ptr[N_NODES] = N_EDGES;
}

// ======== FUSED: GEMM1 (blocks 0..ngemm-1) + edge bucketing (blocks ngemm..) ========
// GEMM1: h8[M,256] = fp8( A[M,256] @ W ). A fp32; W hi/lo bf16 (2 MFMAs: ah*bh + ah*bl;
//        x-lo term dropped — below fp8 output quantization).
// Bucket: CSR scatter of edges, latency-bound, co-resident with GEMM waves -> hides.
#define BM 64
#define BK 32
__global__ __launch_bounds__(256) void gemm1_bucket(
        const float* __restrict__ A,
        const short* __restrict__ Bthi, const short* __restrict__ Btlo,
        unsigned char* __restrict__ h8, int M,
        const int* __restrict__ src, const int* __restrict__ dst,
        const float* __restrict__ dinv, const int* __restrict__ row_ptr,
        int* __restrict__ cursor, unsigned int* __restrict__ erec, int ngemm) {
    __shared__ short sAh[BM * BK];                     // 4KB
    __shared__ short sBh[256 * BK], sBl[256 * BK];     // 16KB + 16KB

    if (blockIdx.x >= ngemm) {
        // ---- bucket_edges body ----
        int e = (blockIdx.x - ngemm) * 256 + threadIdx.x;
        if (e < N_EDGES) {
            int d = dst[e];
            int s = src[e];
            int pos = row_ptr[d] + atomicAdd(&cursor[d], 1);
            unsigned int w = (unsigned int)f2bf(dinv[s] * dinv[d]);
            erec[pos] = (unsigned int)s | (w << 16);
        }
        return;
    }

    // ---- GEMM1 body ----
    int tid = threadIdx.x;
    int wave = tid >> 6, lane = tid & 63;
    int q = lane >> 4, t = lane & 15;
    int row0 = blockIdx.x * BM;
    int wc = wave * 64;            // wave's 64-col slice of N=256

    int lrow = lane >> 2;          // 0..15 (B staging)
    int lk = (lane & 3) * 8;       // k offset (shorts)
    int ar = tid >> 2;             // A staging: row 0..63
    int ak = (tid & 3) * 8;        // A staging: 8 floats at kt+ak

    int ga = row0 + ar; if (ga >= M) ga = M - 1;       // clamp; never stored
    const float* abase = &A[(size_t)ga * 256 + ak];
    float4 a0 = *(const float4*)(abase);
    float4 a1 = *(const float4*)(abase + 4);

    float4v acc[4][4] = {};
    for (int kt = 0; kt < 256; kt += BK) {
#pragma unroll
        for (int j = 0; j < 4; ++j) {
            int n = wave * 64 + j * 16 + lrow;
            size_t boff = (size_t)n * 256 + kt + lk;
            int ldso = wave * 2048 + j * 512 + lane * 8;
            gld_lds16(&Bthi[boff], &sBh[ldso]);
            gld_lds16(&Btlo[boff], &sBl[ldso]);
        }
        {
            short8 h;
            h[0] = (short)f2bf(a0.x); h[1] = (short)f2bf(a0.y);
            h[2] = (short)f2bf(a0.z); h[3] = (short)f2bf(a0.w);
            h[4] = (short)f2bf(a1.x); h[5] = (short)f2bf(a1.y);
            h[6] = (short)f2bf(a1.z); h[7] = (short)f2bf(a1.w);
            *(short8*)&sAh[ar * BK + ak] = h;
        }
        float4 na0 = a0, na1 = a1;
        if (kt + BK < 256) {
            na0 = *(const float4*)(abase + kt + BK);
            na1 = *(const float4*)(abase + kt + BK + 4);
        }
        __syncthreads();
        short8 ah[4], bh[4], bl[4];
#pragma unroll
        for (int mi = 0; mi < 4; ++mi) {
            int r = mi * 16 + t;
            ah[mi] = *(const short8*)&sAh[r * BK + q * 8];
        }
#pragma unroll
        for (int ni = 0; ni < 4; ++ni) {
            int n = wc + ni * 16 + t;
            bh[ni] = *(const short8*)&sBh[n * BK + q * 8];
            bl[ni] = *(const short8*)&sBl[n * BK + q * 8];
        }
#pragma unroll
        for (int mi = 0; mi < 4; ++mi)
#pragma unroll
            for (int ni = 0; ni < 4; ++ni) {
                acc[mi][ni] = __builtin_amdgcn_mfma_f32_16x16x32_bf16(ah[mi], bh[ni], acc[mi][ni], 0, 0, 0);
                acc[mi][ni] = __builtin_amdgcn_mfma_f32_16x16x32_bf16(ah[mi], bl[ni], acc[mi][ni], 0, 0, 0);
            }
        __syncthreads();
        a0 = na0; a1 = na1;
    }
#pragma unroll
    for (int mi = 0; mi < 4; ++mi) {
        int gr0 = row0 + mi * 16 + q * 4;
#pragma unroll
        for (int rr = 0; rr < 4; ++rr) {
            int gr = gr0 + rr;
            if (gr < M) {
#pragma unroll
                for (int ni = 0; ni < 4; ++ni)
                    h8[(size_t)gr * 256 + wc + ni * 16 + t] = fp8_enc(acc[mi][ni][rr]);
            }
        }
    }
}

// ---------------- GEMM2: bf16 A fully preloaded to regs; 2 MFMAs; fp8 out ----------------
__global__ __launch_bounds__(256) void gemm_mfma_bf16(
        const ushort_t* __restrict__ A,   // [M,256] bf16
        const short* __restrict__ Bthi, const short* __restrict__ Btlo,
        unsigned char* __restrict__ h8, int M) {
    __shared__ short sA[BM * BK];                      // 4KB
    __shared__ short sBh[256 * BK], sBl[256 * BK];     // 16KB + 16KB
    int tid = threadIdx.x;
    int wave = tid >> 6, lane = tid & 63;
    int q = lane >> 4, t = lane & 15;
    int row0 = blockIdx.x * BM;
    int wc = wave * 64;

    int lrow = lane >> 2;          // 0..15 (B staging)
    int lk = (lane & 3) * 8;       // k offset (shorts)
    int ar = tid >> 2;             // A staging: row 0..63
    int ak = (tid & 3) * 8;        // 8 shorts at kt+ak

    int ga = row0 + ar; if (ga >= M) ga = M - 1;
    const ushort_t* abase = &A[(size_t)ga * 256 + ak];
    ushort8 areg[8];
#pragma unroll
    for (int i = 0; i < 8; ++i) areg[i] = *(const ushort8*)(abase + i * BK);

    float4v acc[4][4] = {};
#pragma unroll
    for (int ki = 0; ki < 8; ++ki) {
        int kt = ki * BK;
#pragma unroll
        for (int j = 0; j < 4; ++j) {
            int n = wave * 64 + j * 16 + lrow;
            size_t boff = (size_t)n * 256 + kt + lk;
            int ldso = wave * 2048 + j * 512 + lane * 8;
            gld_lds16(&Bthi[boff], &sBh[ldso]);
            gld_lds16(&Btlo[boff], &sBl[ldso]);
        }
        *(ushort8*)&sA[ar * BK + ak] = areg[ki];
        __syncthreads();
        short8 ah[4], bh[4], bl[4];
#pragma unroll
        for (int mi = 0; mi < 4; ++mi) {
            int r = mi * 16 + t;
            ah[mi] = *(const short8*)&sA[r * BK + q * 8];
        }
#pragma unroll
        for (int ni = 0; ni < 4; ++ni) {
            int n = wc + ni * 16 + t;
            bh[ni] = *(const short8*)&sBh[n * BK + q * 8];
            bl[ni] = *(const short8*)&sBl[n * BK + q * 8];
        }
#pragma unroll
        for (int mi = 0; mi < 4; ++mi)
#pragma unroll
            for (int ni = 0; ni < 4; ++ni) {
                acc[mi][ni] = __builtin_amdgcn_mfma_f32_16x16x32_bf16(ah[mi], bh[ni], acc[mi][ni], 0, 0, 0);
                acc[mi][ni] = __builtin_amdgcn_mfma_f32_16x16x32_bf16(ah[mi], bl[ni], acc[mi][ni], 0, 0, 0);
            }
        __syncthreads();
    }
#pragma unroll
    for (int mi = 0; mi < 4; ++mi) {
        int gr0 = row0 + mi * 16 + q * 4;
#pragma unroll
        for (int rr = 0; rr < 4; ++rr) {
            int gr = gr0 + rr;
            if (gr < M) {
#pragma unroll
                for (int ni = 0; ni < 4; ++ni)
                    h8[(size_t)gr * 256 + wc + ni * 16 + t] = fp8_enc(acc[mi][ni][rr]);
            }
        }
    }
}

// -------- CSR gather over fp8 h; 4 groups x 16 lanes x 16 feats (16B), 4 edges in flight --------
// Pads (ev=0) read row 0 with w=0: harmless. h8 loads are CACHED (L2-resident is the point);
// erec loads and output stores are nontemporal (streaming).
__global__ __launch_bounds__(256) void gather_fp8(
        const int* __restrict__ row_ptr, const unsigned int* __restrict__ erec,
        const float* __restrict__ dinv,
        const unsigned char* __restrict__ h8, const float* __restrict__ b,
        ushort_t* __restrict__ outBf) {
    int wave = threadIdx.x >> 6;
    int node = blockIdx.x * 4 + wave;      // N_NODES % 4 == 0
    int lane = threadIdx.x & 63;
    int g = lane >> 4;                      // 4 edge groups
    int hl = lane & 15;                     // feats hl*16 .. +15 (16 fp8 = 16B)
    int beg = row_ptr[node], end = row_ptr[node + 1];
    float dd = dinv[node];
    float acc[16] = {};
    for (int cbeg = beg; cbeg < end; cbeg += 64) {
        int n = end - cbeg; if (n > 64) n = 64;
        unsigned int ev = 0u;
        if (lane < n) ev = __builtin_nontemporal_load(&erec[cbeg + lane]);
        int niter = (n + 15) & ~15;         // pad to x16; pads contribute 0
        for (int k = 0; k < niter; k += 16) {
            unsigned int er0 = (unsigned int)__shfl((int)ev, k + g);
            unsigned int er1 = (unsigned int)__shfl((int)ev, k + 4 + g);
            unsigned int er2 = (unsigned int)__shfl((int)ev, k + 8 + g);
            unsigned int er3 = (unsigned int)__shfl((int)ev, k + 12 + g);
            uint4v p0 = *(const uint4v*)&h8[(size_t)((er0 & 0xFFFFu) * 256u + (unsigned)hl * 16u)];
            uint4v p1 = *(const uint4v*)&h8[(size_t)((er1 & 0xFFFFu) * 256u + (unsigned)hl * 16u)];
            uint4v p2 = *(const uint4v*)&h8[(size_t)((er2 & 0xFFFFu) * 256u + (unsigned)hl * 16u)];
            uint4v p3 = *(const uint4v*)&h8[(size_t)((er3 & 0xFFFFu) * 256u + (unsigned)hl * 16u)];
            float w0 = bf2f((unsigned short)(er0 >> 16));
            float w1 = bf2f((unsigned short)(er1 >> 16));
            float w2 = bf2f((unsigned short)(er2 >> 16));
            float w3 = bf2f((unsigned short)(er3 >> 16));
            float d0[4], d1[4], d2[4], d3[4];
#pragma unroll
            for (int wdi = 0; wdi < 4; ++wdi) {
                fp8x4_dec(p0[wdi], d0);
                fp8x4_dec(p1[wdi], d1);
                fp8x4_dec(p2[wdi], d2);
                fp8x4_dec(p3[wdi], d3);
#pragma unroll
                for (int j = 0; j < 4; ++j) {
                    int a = wdi * 4 + j;
                    acc[a] = fmaf(d0[j], w0, acc[a]);
                    acc[a] = fmaf(d1[j], w1, acc[a]);
                    acc[a] = fmaf(d2[j], w2, acc[a]);
                    acc[a] = fmaf(d3[j], w3, acc[a]);
                }
            }
        }
    }
#pragma unroll
    for (int j = 0; j < 16; ++j) {
        acc[j] += __shfl_xor(acc[j], 16);
        acc[j] += __shfl_xor(acc[j], 32);
    }
    if (g == 0) {
        uint4v sp = *(const uint4v*)&h8[(size_t)node * 256 + hl * 16];
        float sf[16];
        fp8x4_dec(sp[0], &sf[0]);
        fp8x4_dec(sp[1], &sf[4]);
        fp8x4_dec(sp[2], &sf[8]);
        fp8x4_dec(sp[3], &sf[12]);
        float4 b0 = *(const float4*)&b[hl * 16];
        float4 b1 = *(const float4*)&b[hl * 16 + 4];
        float4 b2 = *(const float4*)&b[hl * 16 + 8];
        float4 b3 = *(const float4*)&b[hl * 16 + 12];
        float bb[16] = {b0.x, b0.y, b0.z, b0.w, b1.x, b1.y, b1.z, b1.w,
                        b2.x, b2.y, b2.z, b2.w, b3.x, b3.y, b3.z, b3.w};
        float ws = dd * dd;
        ushort8 o0, o1;
#pragma unroll
        for (int j = 0; j < 8; ++j) {
            float v0 = fmaxf(fmaf(sf[j], ws, acc[j]) + bb[j], 0.f);
            o0[j] = f2bf(v0);
            float v1 = fmaxf(fmaf(sf[8 + j], ws, acc[8 + j]) + bb[8 + j], 0.f);
            o1[j] = f2bf(v1);
        }
        __builtin_nontemporal_store(o0, (ushort8*)&outBf[(size_t)node * 256 + hl * 16]);
        __builtin_nontemporal_store(o1, (ushort8*)&outBf[(size_t)node * 256 + hl * 16 + 8]);
    }
}

// ---------------- parallel triple pooling over bf16 h (1 wave/block) ----------------
__global__ __launch_bounds__(64) void pool_partial(
        const ushort_t* __restrict__ h, const int* __restrict__ batch,
        float* __restrict__ psum, int* __restrict__ pmaxi) {
    int g = blockIdx.x;
    int chunk = blockIdx.y;
    int lane = threadIdx.x;  // 64; lane covers feats lane*4..lane*4+3
    int lo = 0, hi = N_NODES;
    while (lo < hi) { int mid = (lo + hi) >> 1; if (batch[mid] < g) lo = mid + 1; else hi = mid; }
    int start = lo;
    lo = 0; hi = N_NODES;
    while (lo < hi) { int mid = (lo + hi) >> 1; if (batch[mid] < g + 1) lo = mid + 1; else hi = mid; }
    int end = lo;
    int len = end - start;
    if (len <= 0) return;
    int per = (len + POOL_CHUNKS - 1) / POOL_CHUNKS;
    int cs = start + chunk * per;
    int ce = cs + per; if (ce > end) ce = end;
    if (cs >= ce) return;
    float4 sum = make_float4(0.f, 0.f, 0.f, 0.f);
    float4 mx  = make_float4(0.f, 0.f, 0.f, 0.f);
    for (int n = cs; n < ce; ++n) {
        ushort4v u = *(const ushort4v*)&h[(size_t)n * 256 + lane * 4];
        float vx = bf2f(u.x), vy = bf2f(u.y), vz = bf2f(u.z), vw = bf2f(u.w);
        sum.x += vx; sum.y += vy; sum.z += vz; sum.w += vw;
        mx.x = fmaxf(mx.x, vx); mx.y = fmaxf(mx.y, vy);
        mx.z = fmaxf(mx.z, vz); mx.w = fmaxf(mx.w, vw);
    }
    float* ps = &psum[g * F + lane * 4];
    atomicAdd(&ps[0], sum.x); atomicAdd(&ps[1], sum.y);
    atomicAdd(&ps[2], sum.z); atomicAdd(&ps[3], sum.w);
    int* pm = &pmaxi[g * F + lane * 4];
    atomicMax(&pm[0], __float_as_int(mx.x)); atomicMax(&pm[1], __float_as_int(mx.y));
    atomicMax(&pm[2], __float_as_int(mx.z)); atomicMax(&pm[3], __float_as_int(mx.w));
}

// ---------------- final GEMM: out[64,128] = [mean|max|sum] @ Wfc + bfc ----------------
__global__ void final_gemm(const float* __restrict__ psum, const int* __restrict__ pmaxi,
                           const int* __restrict__ batch,
                           const float* __restrict__ Wfc, const float* __restrict__ bfc,
                           float* __restrict__ out) {
    int g = blockIdx.x;   // 64
    int o = threadIdx.x;  // 128
    __shared__ float row[G_DIM];
    __shared__ int s_cnt;
    if (threadIdx.x == 0) {
        int lo = 0, hi = N_NODES;
        while (lo < hi) { int mid = (lo + hi) >> 1; if (batch[mid] < g) lo = mid + 1; else hi = mid; }
        int start = lo;
        lo = 0; hi = N_NODES;
        while (lo < hi) { int mid = (lo + hi) >> 1; if (batch[mid] < g + 1) lo = mid + 1; else hi = mid; }
        s_cnt = lo - start;
    }
    __syncthreads();
    float inv = 1.0f / fmaxf((float)s_cnt, 1.0f);
    for (int i = threadIdx.x; i < F; i += 128) {
        float s = psum[g * F + i];
        row[i]       = s * inv;
        row[F + i]   = __int_as_float(pmaxi[g * F + i]);
        row[2*F + i] = s;
    }
    __syncthreads();
    float acc = bfc[o];
    for (int k = 0; k < G_DIM; ++k) acc += row[k] * Wfc[k * F_OUT + o];
    out[g * F_OUT + o] = acc;
}

extern "C" void kernel_launch(void* const* d_in, const int* in_sizes, int n_in,
                              void* d_out, int out_size, void* d_ws, size_t ws_size,
                              hipStream_t stream) {
    const float* x    = (const float*)d_in[0];
    const int*   ei   = (const int*)d_in[1];
    const int*   batch= (const int*)d_in[2];
    const float* W1   = (const float*)d_in[4];
    const float* b1   = (const float*)d_in[5];
    const float* W2   = (const float*)d_in[6];
    const float* b2   = (const float*)d_in[7];
    const float* Wfc  = (const float*)d_in[8];
    const float* bfc  = (const float*)d_in[9];
    float* out = (float*)d_out;

    const int* src = ei;
    const int* dst = ei + N_EDGES;

    const size_t NF = (size_t)N_NODES * F;   // 12.8M

    unsigned char* h8 = (unsigned char*)d_ws;   // [N,256] fp8 gemm out (12.8 MB)
    ushort_t* h1bf = (ushort_t*)(h8 + NF);      // [N,256] bf16 gather1 out; reused as h2bf
    ushort_t* h2bf = h1bf;                      //   (h1 consumed by gemm2 before gather2 writes)
    short* w1hi  = (short*)(h1bf + NF);         // 4x 64K shorts
    short* w1lo  = w1hi + 65536;
    short* w2hi  = w1lo + 65536;
    short* w2lo  = w2hi + 65536;
    float* dinv  = (float*)(w2lo + 65536);   // [N]
    // ---- contiguous zero-init region: deg, cursor, psum, pmaxi ----
    int*   deg   = (int*)(dinv + N_NODES);   // [N]
    int*   cursor= deg + N_NODES;            // [N]
    float* psum  = (float*)(cursor + N_NODES);   // [64][256]
    int*   pmaxi = (int*)(psum + N_GRAPHS * F);  // [64][256]
    // ---- rest ----
    int*   row_ptr = pmaxi + N_GRAPHS * F;   // [N+1]
    int*   btot  = row_ptr + N_NODES + 1;    // [256]
    unsigned int* erec = (unsigned int*)(btot + 256);   // [E] 4B records (3.2 MB)

    // ---- degree + norm + CSR prep (+ W casts fused); ONE memset for all zeroed buffers ----
    hipMemsetAsync(deg, 0, (2 * N_NODES + 2 * N_GRAPHS * F) * sizeof(int), stream);
    prep_w_deg<<<512 + (N_EDGES + 255) / 256, 256, 0, stream>>>(
        W1, W2, w1hi, w1lo, w2hi, w2lo, dst, deg);
    scan_blocks<<<SCAN_NB, 256, 0, stream>>>(deg, row_ptr, btot, dinv);
    add_offsets<<<SCAN_NB, 256, 0, stream>>>(row_ptr, btot);

    int ggemm = (N_NODES + BM - 1) / BM;      // 782
    int ngb = N_NODES / 4;                    // 12500 blocks of 4 waves

    // ---- layer 1 (GEMM fused with edge bucketing; independent work co-scheduled) ----
    gemm1_bucket<<<ggemm + EBLK, 256, 0, stream>>>(
        x, w1hi, w1lo, h8, N_NODES, src, dst, dinv, row_ptr, cursor, erec, ggemm);
    gather_fp8<<<ngb, 256, 0, stream>>>(row_ptr, erec, dinv, h8, b1, h1bf);

    // ---- layer 2 ----
    gemm_mfma_bf16<<<ggemm, 256, 0, stream>>>(h1bf, w2hi, w2lo, h8, N_NODES);
    gather_fp8<<<ngb, 256, 0, stream>>>(row_ptr, erec, dinv, h8, b2, h2bf);

    // ---- pooling + classifier ----
    pool_partial<<<dim3(N_GRAPHS, POOL_CHUNKS), 64, 0, stream>>>(h2bf, batch, psum, pmaxi);
    final_gemm<<<N_GRAPHS, F_OUT, 0, stream>>>(psum, pmaxi, batch, Wfc, bfc, out);
}

// Round 8
// 329.991 us; speedup vs baseline: 1.8504x; 1.0609x over previous
//
#include <hip/hip_runtime.h>

#define N_NODES 50000
#define N_EDGES 800000
#define N_GRAPHS 64
#define F 256        // F_IN == F_HID
#define F_OUT 128
#define G_DIM 768    // 3*F
#define SCAN_NB ((N_NODES + 255) / 256)   // 196
#define POOL_CHUNKS 32
#define EBLK ((N_EDGES + 255) / 256)      // 3125

typedef unsigned short ushort_t;
typedef short short8 __attribute__((ext_vector_type(8)));
typedef unsigned short ushort8 __attribute__((ext_vector_type(8)));
typedef unsigned short ushort4v __attribute__((ext_vector_type(4)));
typedef float float4v __attribute__((ext_vector_type(4)));
typedef float f32x2 __attribute__((ext_vector_type(2)));
typedef unsigned int uint4v __attribute__((ext_vector_type(4)));

// ---- bf16 helpers (RNE) ----
__device__ __forceinline__ unsigned short f2bf(float f) {
    unsigned int u = __float_as_uint(f);
    u += 0x7FFFu + ((u >> 16) & 1u);
    return (unsigned short)(u >> 16);
}
__device__ __forceinline__ float bf2f(unsigned short s) {
    return __uint_as_float(((unsigned int)s) << 16);
}

// ---- fp8 e4m3 encode/decode: HW cvt when available, exact bit-trick fallback ----
__device__ __forceinline__ unsigned char fp8_enc(float v) {
#if __has_builtin(__builtin_amdgcn_cvt_pk_fp8_f32)
    return (unsigned char)__builtin_amdgcn_cvt_pk_fp8_f32(v, v, 0, false);
#else
    float x = v * 0x1p-120f;                    // align e4m3 to f32 bits 27..20
    unsigned int u = __float_as_uint(x);
    unsigned int mag = u & 0x7FFFFFFFu;
    unsigned int r = mag + 0x0007FFFFu + ((mag >> 20) & 1u);   // RNE at bit 20
    unsigned int em = r >> 20;
    if (em > 0x7Eu) em = 0x7Eu;                 // clamp to +-448, no NaN
    return (unsigned char)(em | ((u >> 24) & 0x80u));
#endif
}

// decode 4 fp8 (one u32) -> 4 floats
__device__ __forceinline__ void fp8x4_dec(unsigned int u, float* o) {
#if __has_builtin(__builtin_amdgcn_cvt_pk_f32_fp8)
    f32x2 d0 = __builtin_amdgcn_cvt_pk_f32_fp8((int)u, false);
    f32x2 d1 = __builtin_amdgcn_cvt_pk_f32_fp8((int)u, true);
    o[0] = d0[0]; o[1] = d0[1]; o[2] = d1[0]; o[3] = d1[1];
#else
#pragma unroll
    for (int i = 0; i < 4; ++i) {
        unsigned int b = (u >> (8 * i)) & 0xFFu;
        unsigned int bits = ((b & 0x7Fu) << 20) | ((b & 0x80u) << 24);
        o[i] = __uint_as_float(bits) * 0x1p+120f;   // exact incl. subnormals
    }
#endif
}

// ---- async global->LDS, 16B per lane; LDS dest = wave-uniform base + lane*16 ----
__device__ __forceinline__ void gld_lds16(const void* gsrc, void* ldst) {
    __builtin_amdgcn_global_load_lds(
        (const __attribute__((address_space(1))) unsigned int*)gsrc,
        (__attribute__((address_space(3))) unsigned int*)ldst, 16, 0, 0);
}

// ------- fused: W1/W2 transposed hi/lo cast (blocks 0..511) + degree count + edge rank -------
// rank[e] = this edge's arrival index at its dst -> bucket pass needs NO atomic.
__global__ void prep_w_deg(const float* __restrict__ W1, const float* __restrict__ W2,
                           short* __restrict__ hi1, short* __restrict__ lo1,
                           short* __restrict__ hi2, short* __restrict__ lo2,
                           const int* __restrict__ dst, int* __restrict__ deg,
                           int* __restrict__ rank) {
    int blk = blockIdx.x;
    if (blk < 512) {
        const float* W = (blk < 256) ? W1 : W2;
        short* hi = (blk < 256) ? hi1 : hi2;
        short* lo = (blk < 256) ? lo1 : lo2;
        int n = blk & 255;
        int k = threadIdx.x;
        float v = W[k * 256 + n];
        unsigned short h = f2bf(v);
        hi[n * 256 + k] = (short)h;
        lo[n * 256 + k] = (short)f2bf(v - bf2f(h));
    } else {
        int e = (blk - 512) * 256 + threadIdx.x;
        if (e < N_EDGES) rank[e] = atomicAdd(&deg[dst[e]], 1);
    }
}

// ---------------- scan blocks + fused dinv (btot holds RAW per-block sums) ----------------
__global__ void scan_blocks(const int* __restrict__ deg, int* __restrict__ row_ptr,
                            int* __restrict__ block_tot, float* __restrict__ dinv) {
    __shared__ int sd[256];
    int t = threadIdx.x;
    int idx = blockIdx.x * 256 + t;
    int v = (idx < N_NODES) ? deg[idx] : 0;
    if (idx < N_NODES) dinv[idx] = rsqrtf((float)(v + 1));   // +1 self-loop
    sd[t] = v;
    __syncthreads();
    for (int off = 1; off < 256; off <<= 1) {
        int a = (t >= off) ? sd[t - off] : 0;
        __syncthreads();
        sd[t] += a;
        __syncthreads();
    }
    if (idx < N_NODES) row_ptr[idx] = sd[t] - v;
    if (t == 255) block_tot[blockIdx.x] = sd[255];
}

// ------- add block offsets; also emit packed per-node record rpd = {row_ptr, dinv bits} -------
__global__ void add_offsets(int* __restrict__ row_ptr, const int* __restrict__ block_tot,
                            const float* __restrict__ dinv, int2* __restrict__ rpd) {
    __shared__ int sd[256];
    int t = threadIdx.x;
    int blk = blockIdx.x;
    sd[t] = (t < blk && t < SCAN_NB) ? block_tot[t] : 0;
    __syncthreads();
    for (int off = 128; off > 0; off >>= 1) {
        if (t < off) sd[t] += sd[t + off];
        __syncthreads();
    }
    int base = sd[0];
    int idx = blk * 256 + t;
    if (idx < N_NODES) {
        int fin = row_ptr[idx] + base;
        row_ptr[idx] = fin;
        rpd[idx] = make_int2(fin, __float_as_int(dinv[idx]));
    }
    if (idx == 0) row_ptr[N_NODES] = N_EDGES;
}

// ======== FUSED: GEMM1 (blocks 0..ngemm-1) + atomic-free edge bucketing (rest) ========
// GEMM1: h8[M,256] = fp8( A[M,256] @ W ). A fp32; W hi/lo bf16 (2 MFMAs).
// Bucket: pos = rpd[d].x + rank[e]  (no atomic; 1 random 8B load + 1 random 4B + store).
#define BM 64
#define BK 32
__global__ __launch_bounds__(256) void gemm1_bucket(
        const float* __restrict__ A,
        const short* __restrict__ Bthi, const short* __restrict__ Btlo,
        unsigned char* __restrict__ h8, int M,
        const int* __restrict__ src, const int* __restrict__ dst,
        const float* __restrict__ dinv, const int* __restrict__ rank,
        const int2* __restrict__ rpd, unsigned int* __restrict__ erec, int ngemm) {
    __shared__ short sAh[BM * BK];                     // 4KB
    __shared__ short sBh[256 * BK], sBl[256 * BK];     // 16KB + 16KB

    if (blockIdx.x >= ngemm) {
        // ---- bucket body: atomic-free CSR scatter ----
        int e = (blockIdx.x - ngemm) * 256 + threadIdx.x;
        if (e < N_EDGES) {
            int d = dst[e];
            int s = src[e];
            int rk = rank[e];
            int2 rd = rpd[d];                          // {row_ptr[d], dinv[d]}
            float ws = __int_as_float(rd.y) * dinv[s];
            unsigned int w = (unsigned int)f2bf(ws);
            erec[rd.x + rk] = (unsigned int)s | (w << 16);
        }
        return;
    }

    // ---- GEMM1 body ----
    int tid = threadIdx.x;
    int wave = tid >> 6, lane = tid & 63;
    int q = lane >> 4, t = lane & 15;
    int row0 = blockIdx.x * BM;
    int wc = wave * 64;            // wave's 64-col slice of N=256

    int lrow = lane >> 2;          // 0..15 (B staging)
    int lk = (lane & 3) * 8;       // k offset (shorts)
    int ar = tid >> 2;             // A staging: row 0..63
    int ak = (tid & 3) * 8;        // A staging: 8 floats at kt+ak

    int ga = row0 + ar; if (ga >= M) ga = M - 1;       // clamp; never stored
    const float* abase = &A[(size_t)ga * 256 + ak];
    float4 a0 = *(const float4*)(abase);
    float4 a1 = *(const float4*)(abase + 4);

    float4v acc[4][4] = {};
    for (int kt = 0; kt < 256; kt += BK) {
#pragma unroll
        for (int j = 0; j < 4; ++j) {
            int n = wave * 64 + j * 16 + lrow;
            size_t boff = (size_t)n * 256 + kt + lk;
            int ldso = wave * 2048 + j * 512 + lane * 8;
            gld_lds16(&Bthi[boff], &sBh[ldso]);
            gld_lds16(&Btlo[boff], &sBl[ldso]);
        }
        {
            short8 h;
            h[0] = (short)f2bf(a0.x); h[1] = (short)f2bf(a0.y);
            h[2] = (short)f2bf(a0.z); h[3] = (short)f2bf(a0.w);
            h[4] = (short)f2bf(a1.x); h[5] = (short)f2bf(a1.y);
            h[6] = (short)f2bf(a1.z); h[7] = (short)f2bf(a1.w);
            *(short8*)&sAh[ar * BK + ak] = h;
        }
        float4 na0 = a0, na1 = a1;
        if (kt + BK < 256) {
            na0 = *(const float4*)(abase + kt + BK);
            na1 = *(const float4*)(abase + kt + BK + 4);
        }
        __syncthreads();
        short8 ah[4], bh[4], bl[4];
#pragma unroll
        for (int mi = 0; mi < 4; ++mi) {
            int r = mi * 16 + t;
            ah[mi] = *(const short8*)&sAh[r * BK + q * 8];
        }
#pragma unroll
        for (int ni = 0; ni < 4; ++ni) {
            int n = wc + ni * 16 + t;
            bh[ni] = *(const short8*)&sBh[n * BK + q * 8];
            bl[ni] = *(const short8*)&sBl[n * BK + q * 8];
        }
#pragma unroll
        for (int mi = 0; mi < 4; ++mi)
#pragma unroll
            for (int ni = 0; ni < 4; ++ni) {
                acc[mi][ni] = __builtin_amdgcn_mfma_f32_16x16x32_bf16(ah[mi], bh[ni], acc[mi][ni], 0, 0, 0);
                acc[mi][ni] = __builtin_amdgcn_mfma_f32_16x16x32_bf16(ah[mi], bl[ni], acc[mi][ni], 0, 0, 0);
            }
        __syncthreads();
        a0 = na0; a1 = na1;
    }
#pragma unroll
    for (int mi = 0; mi < 4; ++mi) {
        int gr0 = row0 + mi * 16 + q * 4;
#pragma unroll
        for (int rr = 0; rr < 4; ++rr) {
            int gr = gr0 + rr;
            if (gr < M) {
#pragma unroll
                for (int ni = 0; ni < 4; ++ni)
                    h8[(size_t)gr * 256 + wc + ni * 16 + t] = fp8_enc(acc[mi][ni][rr]);
            }
        }
    }
}

// ---------------- GEMM2: bf16 A fully preloaded to regs; 2 MFMAs; fp8 out ----------------
__global__ __launch_bounds__(256) void gemm_mfma_bf16(
        const ushort_t* __restrict__ A,   // [M,256] bf16
        const short* __restrict__ Bthi, const short* __restrict__ Btlo,
        unsigned char* __restrict__ h8, int M) {
    __shared__ short sA[BM * BK];                      // 4KB
    __shared__ short sBh[256 * BK], sBl[256 * BK];     // 16KB + 16KB
    int tid = threadIdx.x;
    int wave = tid >> 6, lane = tid & 63;
    int q = lane >> 4, t = lane & 15;
    int row0 = blockIdx.x * BM;
    int wc = wave * 64;

    int lrow = lane >> 2;          // 0..15 (B staging)
    int lk = (lane & 3) * 8;       // k offset (shorts)
    int ar = tid >> 2;             // A staging: row 0..63
    int ak = (tid & 3) * 8;        // 8 shorts at kt+ak

    int ga = row0 + ar; if (ga >= M) ga = M - 1;
    const ushort_t* abase = &A[(size_t)ga * 256 + ak];
    ushort8 areg[8];
#pragma unroll
    for (int i = 0; i < 8; ++i) areg[i] = *(const ushort8*)(abase + i * BK);

    float4v acc[4][4] = {};
#pragma unroll
    for (int ki = 0; ki < 8; ++ki) {
        int kt = ki * BK;
#pragma unroll
        for (int j = 0; j < 4; ++j) {
            int n = wave * 64 + j * 16 + lrow;
            size_t boff = (size_t)n * 256 + kt + lk;
            int ldso = wave * 2048 + j * 512 + lane * 8;
            gld_lds16(&Bthi[boff], &sBh[ldso]);
            gld_lds16(&Btlo[boff], &sBl[ldso]);
        }
        *(ushort8*)&sA[ar * BK + ak] = areg[ki];
        __syncthreads();
        short8 ah[4], bh[4], bl[4];
#pragma unroll
        for (int mi = 0; mi < 4; ++mi) {
            int r = mi * 16 + t;
            ah[mi] = *(const short8*)&sA[r * BK + q * 8];
        }
#pragma unroll
        for (int ni = 0; ni < 4; ++ni) {
            int n = wc + ni * 16 + t;
            bh[ni] = *(const short8*)&sBh[n * BK + q * 8];
            bl[ni] = *(const short8*)&sBl[n * BK + q * 8];
        }
#pragma unroll
        for (int mi = 0; mi < 4; ++mi)
#pragma unroll
            for (int ni = 0; ni < 4; ++ni) {
                acc[mi][ni] = __builtin_amdgcn_mfma_f32_16x16x32_bf16(ah[mi], bh[ni], acc[mi][ni], 0, 0, 0);
                acc[mi][ni] = __builtin_amdgcn_mfma_f32_16x16x32_bf16(ah[mi], bl[ni], acc[mi][ni], 0, 0, 0);
            }
        __syncthreads();
    }
#pragma unroll
    for (int mi = 0; mi < 4; ++mi) {
        int gr0 = row0 + mi * 16 + q * 4;
#pragma unroll
        for (int rr = 0; rr < 4; ++rr) {
            int gr = gr0 + rr;
            if (gr < M) {
#pragma unroll
                for (int ni = 0; ni < 4; ++ni)
                    h8[(size_t)gr * 256 + wc + ni * 16 + t] = fp8_enc(acc[mi][ni][rr]);
            }
        }
    }
}

// -------- CSR gather over fp8 h; 4 groups x 16 lanes x 16 feats (16B), 4 edges in flight --------
// Pads (ev=0) read row 0 with w=0: harmless. h8 loads are CACHED (L2-resident is the point);
// erec loads and output stores are nontemporal (streaming).
__global__ __launch_bounds__(256) void gather_fp8(
        const int* __restrict__ row_ptr, const unsigned int* __restrict__ erec,
        const float* __restrict__ dinv,
        const unsigned char* __restrict__ h8, const float* __restrict__ b,
        ushort_t* __restrict__ outBf) {
    int wave = threadIdx.x >> 6;
    int node = blockIdx.x * 4 + wave;      // N_NODES % 4 == 0
    int lane = threadIdx.x & 63;
    int g = lane >> 4;                      // 4 edge groups
    int hl = lane & 15;                     // feats hl*16 .. +15 (16 fp8 = 16B)
    int beg = row_ptr[node], end = row_ptr[node + 1];
    float dd = dinv[node];
    float acc[16] = {};
    for (int cbeg = beg; cbeg < end; cbeg += 64) {
        int n = end - cbeg; if (n > 64) n = 64;
        unsigned int ev = 0u;
        if (lane < n) ev = __builtin_nontemporal_load(&erec[cbeg + lane]);
        int niter = (n + 15) & ~15;         // pad to x16; pads contribute 0
        for (int k = 0; k < niter; k += 16) {
            unsigned int er0 = (unsigned int)__shfl((int)ev, k + g);
            unsigned int er1 = (unsigned int)__shfl((int)ev, k + 4 + g);
            unsigned int er2 = (unsigned int)__shfl((int)ev, k + 8 + g);
            unsigned int er3 = (unsigned int)__shfl((int)ev, k + 12 + g);
            uint4v p0 = *(const uint4v*)&h8[(size_t)((er0 & 0xFFFFu) * 256u + (unsigned)hl * 16u)];
            uint4v p1 = *(const uint4v*)&h8[(size_t)((er1 & 0xFFFFu) * 256u + (unsigned)hl * 16u)];
            uint4v p2 = *(const uint4v*)&h8[(size_t)((er2 & 0xFFFFu) * 256u + (unsigned)hl * 16u)];
            uint4v p3 = *(const uint4v*)&h8[(size_t)((er3 & 0xFFFFu) * 256u + (unsigned)hl * 16u)];
            float w0 = bf2f((unsigned short)(er0 >> 16));
            float w1 = bf2f((unsigned short)(er1 >> 16));
            float w2 = bf2f((unsigned short)(er2 >> 16));
            float w3 = bf2f((unsigned short)(er3 >> 16));
            float d0[4], d1[4], d2[4], d3[4];
#pragma unroll
            for (int wdi = 0; wdi < 4; ++wdi) {
                fp8x4_dec(p0[wdi], d0);
                fp8x4_dec(p1[wdi], d1);
                fp8x4_dec(p2[wdi], d2);
                fp8x4_dec(p3[wdi], d3);
#pragma unroll
                for (int j = 0; j < 4; ++j) {
                    int a = wdi * 4 + j;
                    acc[a] = fmaf(d0[j], w0, acc[a]);
                    acc[a] = fmaf(d1[j], w1, acc[a]);
                    acc[a] = fmaf(d2[j], w2, acc[a]);
                    acc[a] = fmaf(d3[j], w3, acc[a]);
                }
            }
        }
    }
#pragma unroll
    for (int j = 0; j < 16; ++j) {
        acc[j] += __shfl_xor(acc[j], 16);
        acc[j] += __shfl_xor(acc[j], 32);
    }
    if (g == 0) {
        uint4v sp = *(const uint4v*)&h8[(size_t)node * 256 + hl * 16];
        float sf[16];
        fp8x4_dec(sp[0], &sf[0]);
        fp8x4_dec(sp[1], &sf[4]);
        fp8x4_dec(sp[2], &sf[8]);
        fp8x4_dec(sp[3], &sf[12]);
        float4 b0 = *(const float4*)&b[hl * 16];
        float4 b1 = *(const float4*)&b[hl * 16 + 4];
        float4 b2 = *(const float4*)&b[hl * 16 + 8];
        float4 b3 = *(const float4*)&b[hl * 16 + 12];
        float bb[16] = {b0.x, b0.y, b0.z, b0.w, b1.x, b1.y, b1.z, b1.w,
                        b2.x, b2.y, b2.z, b2.w, b3.x, b3.y, b3.z, b3.w};
        float ws = dd * dd;
        ushort8 o0, o1;
#pragma unroll
        for (int j = 0; j < 8; ++j) {
            float v0 = fmaxf(fmaf(sf[j], ws, acc[j]) + bb[j], 0.f);
            o0[j] = f2bf(v0);
            float v1 = fmaxf(fmaf(sf[8 + j], ws, acc[8 + j]) + bb[8 + j], 0.f);
            o1[j] = f2bf(v1);
        }
        __builtin_nontemporal_store(o0, (ushort8*)&outBf[(size_t)node * 256 + hl * 16]);
        __builtin_nontemporal_store(o1, (ushort8*)&outBf[(size_t)node * 256 + hl * 16 + 8]);
    }
}

// ---------------- parallel triple pooling over bf16 h (1 wave/block) ----------------
__global__ __launch_bounds__(64) void pool_partial(
        const ushort_t* __restrict__ h, const int* __restrict__ batch,
        float* __restrict__ psum, int* __restrict__ pmaxi) {
    int g = blockIdx.x;
    int chunk = blockIdx.y;
    int lane = threadIdx.x;  // 64; lane covers feats lane*4..lane*4+3
    int lo = 0, hi = N_NODES;
    while (lo < hi) { int mid = (lo + hi) >> 1; if (batch[mid] < g) lo = mid + 1; else hi = mid; }
    int start = lo;
    lo = 0; hi = N_NODES;
    while (lo < hi) { int mid = (lo + hi) >> 1; if (batch[mid] < g + 1) lo = mid + 1; else hi = mid; }
    int end = lo;
    int len = end - start;
    if (len <= 0) return;
    int per = (len + POOL_CHUNKS - 1) / POOL_CHUNKS;
    int cs = start + chunk * per;
    int ce = cs + per; if (ce > end) ce = end;
    if (cs >= ce) return;
    float4 sum = make_float4(0.f, 0.f, 0.f, 0.f);
    float4 mx  = make_float4(0.f, 0.f, 0.f, 0.f);
    for (int n = cs; n < ce; ++n) {
        ushort4v u = *(const ushort4v*)&h[(size_t)n * 256 + lane * 4];
        float vx = bf2f(u.x), vy = bf2f(u.y), vz = bf2f(u.z), vw = bf2f(u.w);
        sum.x += vx; sum.y += vy; sum.z += vz; sum.w += vw;
        mx.x = fmaxf(mx.x, vx); mx.y = fmaxf(mx.y, vy);
        mx.z = fmaxf(mx.z, vz); mx.w = fmaxf(mx.w, vw);
    }
    float* ps = &psum[g * F + lane * 4];
    atomicAdd(&ps[0], sum.x); atomicAdd(&ps[1], sum.y);
    atomicAdd(&ps[2], sum.z); atomicAdd(&ps[3], sum.w);
    int* pm = &pmaxi[g * F + lane * 4];
    atomicMax(&pm[0], __float_as_int(mx.x)); atomicMax(&pm[1], __float_as_int(mx.y));
    atomicMax(&pm[2], __float_as_int(mx.z)); atomicMax(&pm[3], __float_as_int(mx.w));
}

// ---------------- final GEMM: out[64,128] = [mean|max|sum] @ Wfc + bfc ----------------
__global__ void final_gemm(const float* __restrict__ psum, const int* __restrict__ pmaxi,
                           const int* __restrict__ batch,
                           const float* __restrict__ Wfc, const float* __restrict__ bfc,
                           float* __restrict__ out) {
    int g = blockIdx.x;   // 64
    int o = threadIdx.x;  // 128
    __shared__ float row[G_DIM];
    __shared__ int s_cnt;
    if (threadIdx.x == 0) {
        int lo = 0, hi = N_NODES;
        while (lo < hi) { int mid = (lo + hi) >> 1; if (batch[mid] < g) lo = mid + 1; else hi = mid; }
        int start = lo;
        lo = 0; hi = N_NODES;
        while (lo < hi) { int mid = (lo + hi) >> 1; if (batch[mid] < g + 1) lo = mid + 1; else hi = mid; }
        s_cnt = lo - start;
    }
    __syncthreads();
    float inv = 1.0f / fmaxf((float)s_cnt, 1.0f);
    for (int i = threadIdx.x; i < F; i += 128) {
        float s = psum[g * F + i];
        row[i]       = s * inv;
        row[F + i]   = __int_as_float(pmaxi[g * F + i]);
        row[2*F + i] = s;
    }
    __syncthreads();
    float acc = bfc[o];
    for (int k = 0; k < G_DIM; ++k) acc += row[k] * Wfc[k * F_OUT + o];
    out[g * F_OUT + o] = acc;
}

extern "C" void kernel_launch(void* const* d_in, const int* in_sizes, int n_in,
                              void* d_out, int out_size, void* d_ws, size_t ws_size,
                              hipStream_t stream) {
    const float* x    = (const float*)d_in[0];
    const int*   ei   = (const int*)d_in[1];
    const int*   batch= (const int*)d_in[2];
    const float* W1   = (const float*)d_in[4];
    const float* b1   = (const float*)d_in[5];
    const float* W2   = (const float*)d_in[6];
    const float* b2   = (const float*)d_in[7];
    const float* Wfc  = (const float*)d_in[8];
    const float* bfc  = (const float*)d_in[9];
    float* out = (float*)d_out;

    const int* src = ei;
    const int* dst = ei + N_EDGES;

    const size_t NF = (size_t)N_NODES * F;   // 12.8M

    unsigned char* h8 = (unsigned char*)d_ws;   // [N,256] fp8 gemm out (12.8 MB)
    ushort_t* h1bf = (ushort_t*)(h8 + NF);      // [N,256] bf16 gather1 out; reused as h2bf
    ushort_t* h2bf = h1bf;                      //   (h1 consumed by gemm2 before gather2 writes)
    short* w1hi  = (short*)(h1bf + NF);         // 4x 64K shorts
    short* w1lo  = w1hi + 65536;
    short* w2hi  = w1lo + 65536;
    short* w2lo  = w2hi + 65536;
    float* dinv  = (float*)(w2lo + 65536);   // [N]
    // ---- contiguous zero-init region: deg, psum, pmaxi ----
    int*   deg   = (int*)(dinv + N_NODES);       // [N]
    float* psum  = (float*)(deg + N_NODES);      // [64][256]
    int*   pmaxi = (int*)(psum + N_GRAPHS * F);  // [64][256]
    // ---- rest (all fully overwritten each run; no init needed) ----
    int2*  rpd   = (int2*)(pmaxi + N_GRAPHS * F);   // [N] {row_ptr, dinv bits} (8B aligned)
    int*   row_ptr = (int*)(rpd + N_NODES);      // [N+1]
    int*   btot  = row_ptr + N_NODES + 1;        // [256]
    unsigned int* erec = (unsigned int*)(btot + 256 + 1);   // [E] 4B records (3.2 MB)
    int*   rank  = (int*)(erec + N_EDGES);       // [E] per-edge rank at dst (3.2 MB)

    // ---- degree + rank + norm + CSR prep (+ W casts fused) ----
    hipMemsetAsync(deg, 0, (N_NODES + 2 * N_GRAPHS * F) * sizeof(int), stream);
    prep_w_deg<<<512 + EBLK, 256, 0, stream>>>(
        W1, W2, w1hi, w1lo, w2hi, w2lo, dst, deg, rank);
    scan_blocks<<<SCAN_NB, 256, 0, stream>>>(deg, row_ptr, btot, dinv);
    add_offsets<<<SCAN_NB, 256, 0, stream>>>(row_ptr, btot, dinv, rpd);

    int ggemm = (N_NODES + BM - 1) / BM;      // 782
    int ngb = N_NODES / 4;                    // 12500 blocks of 4 waves

    // ---- layer 1 (GEMM fused with atomic-free edge bucketing) ----
    gemm1_bucket<<<ggemm + EBLK, 256, 0, stream>>>(
        x, w1hi, w1lo, h8, N_NODES, src, dst, dinv, rank, rpd, erec, ggemm);
    gather_fp8<<<ngb, 256, 0, stream>>>(row_ptr, erec, dinv, h8, b1, h1bf);

    // ---- layer 2 ----
    gemm_mfma_bf16<<<ggemm, 256, 0, stream>>>(h1bf, w2hi, w2lo, h8, N_NODES);
    gather_fp8<<<ngb, 256, 0, stream>>>(row_ptr, erec, dinv, h8, b2, h2bf);

    // ---- pooling + classifier ----
    pool_partial<<<dim3(N_GRAPHS, POOL_CHUNKS), 64, 0, stream>>>(h2bf, batch, psum, pmaxi);
    final_gemm<<<N_GRAPHS, F_OUT, 0, stream>>>(psum, pmaxi, batch, Wfc, bfc, out);
}

// Round 9
// 309.987 us; speedup vs baseline: 1.9699x; 1.0645x over previous
//
#include <hip/hip_runtime.h>

#define N_NODES 50000
#define N_EDGES 800000
#define N_GRAPHS 64
#define F 256        // F_IN == F_HID
#define F_OUT 128
#define G_DIM 768    // 3*F
#define SCAN_NB ((N_NODES + 255) / 256)   // 196
#define POOL_CHUNKS 32
#define EBLK4 ((N_EDGES + 1023) / 1024)   // 782 (4 edges/thread)

typedef unsigned short ushort_t;
typedef short short8 __attribute__((ext_vector_type(8)));
typedef unsigned short ushort8 __attribute__((ext_vector_type(8)));
typedef unsigned short ushort4v __attribute__((ext_vector_type(4)));
typedef float float4v __attribute__((ext_vector_type(4)));
typedef float f32x2 __attribute__((ext_vector_type(2)));
typedef unsigned int uint4v __attribute__((ext_vector_type(4)));

// ---- bf16 helpers (RNE) ----
__device__ __forceinline__ unsigned short f2bf(float f) {
    unsigned int u = __float_as_uint(f);
    u += 0x7FFFu + ((u >> 16) & 1u);
    return (unsigned short)(u >> 16);
}
__device__ __forceinline__ float bf2f(unsigned short s) {
    return __uint_as_float(((unsigned int)s) << 16);
}

// ---- fp8 e4m3 encode/decode: HW cvt when available, exact bit-trick fallback ----
__device__ __forceinline__ unsigned char fp8_enc(float v) {
#if __has_builtin(__builtin_amdgcn_cvt_pk_fp8_f32)
    return (unsigned char)__builtin_amdgcn_cvt_pk_fp8_f32(v, v, 0, false);
#else
    float x = v * 0x1p-120f;                    // align e4m3 to f32 bits 27..20
    unsigned int u = __float_as_uint(x);
    unsigned int mag = u & 0x7FFFFFFFu;
    unsigned int r = mag + 0x0007FFFFu + ((mag >> 20) & 1u);   // RNE at bit 20
    unsigned int em = r >> 20;
    if (em > 0x7Eu) em = 0x7Eu;                 // clamp to +-448, no NaN
    return (unsigned char)(em | ((u >> 24) & 0x80u));
#endif
}

// decode 4 fp8 (one u32) -> 4 floats
__device__ __forceinline__ void fp8x4_dec(unsigned int u, float* o) {
#if __has_builtin(__builtin_amdgcn_cvt_pk_f32_fp8)
    f32x2 d0 = __builtin_amdgcn_cvt_pk_f32_fp8((int)u, false);
    f32x2 d1 = __builtin_amdgcn_cvt_pk_f32_fp8((int)u, true);
    o[0] = d0[0]; o[1] = d0[1]; o[2] = d1[0]; o[3] = d1[1];
#else
#pragma unroll
    for (int i = 0; i < 4; ++i) {
        unsigned int b = (u >> (8 * i)) & 0xFFu;
        unsigned int bits = ((b & 0x7Fu) << 20) | ((b & 0x80u) << 24);
        o[i] = __uint_as_float(bits) * 0x1p+120f;   // exact incl. subnormals
    }
#endif
}

// ---- async global->LDS, 16B per lane; LDS dest = wave-uniform base + lane*16 ----
__device__ __forceinline__ void gld_lds16(const void* gsrc, void* ldst) {
    __builtin_amdgcn_global_load_lds(
        (const __attribute__((address_space(1))) unsigned int*)gsrc,
        (__attribute__((address_space(3))) unsigned int*)ldst, 16, 0, 0);
}

// ------- fused: W1/W2 transposed bf16 cast (blocks 0..511) + deg count + edge rank -------
// W-lo dropped: h is fp8-quantized (~3%), bf16 weight error (~0.4%) is negligible.
// Edge pass: 4 edges/thread, coalesced int4 loads, 4 independent atomics in flight.
__global__ void prep_w_deg(const float* __restrict__ W1, const float* __restrict__ W2,
                           short* __restrict__ hi1, short* __restrict__ hi2,
                           const int* __restrict__ dst, int* __restrict__ deg,
                           int* __restrict__ rank) {
    int blk = blockIdx.x;
    if (blk < 512) {
        const float* W = (blk < 256) ? W1 : W2;
        short* hi = (blk < 256) ? hi1 : hi2;
        int n = blk & 255;
        int k = threadIdx.x;
        hi[n * 256 + k] = (short)f2bf(W[k * 256 + n]);
    } else {
        int eb = (blk - 512) * 1024 + threadIdx.x * 4;
        if (eb < N_EDGES) {                       // N_EDGES%4==0 -> int4 safe
            int4 d4 = *(const int4*)&dst[eb];
            int r0 = atomicAdd(&deg[d4.x], 1);
            int r1 = atomicAdd(&deg[d4.y], 1);
            int r2 = atomicAdd(&deg[d4.z], 1);
            int r3 = atomicAdd(&deg[d4.w], 1);
            *(int4*)&rank[eb] = make_int4(r0, r1, r2, r3);
        }
    }
}

// ---------------- scan blocks + fused dinv (btot holds RAW per-block sums) ----------------
__global__ void scan_blocks(const int* __restrict__ deg, int* __restrict__ row_ptr,
                            int* __restrict__ block_tot, float* __restrict__ dinv) {
    __shared__ int sd[256];
    int t = threadIdx.x;
    int idx = blockIdx.x * 256 + t;
    int v = (idx < N_NODES) ? deg[idx] : 0;
    if (idx < N_NODES) dinv[idx] = rsqrtf((float)(v + 1));   // +1 self-loop
    sd[t] = v;
    __syncthreads();
    for (int off = 1; off < 256; off <<= 1) {
        int a = (t >= off) ? sd[t - off] : 0;
        __syncthreads();
        sd[t] += a;
        __syncthreads();
    }
    if (idx < N_NODES) row_ptr[idx] = sd[t] - v;
    if (t == 255) block_tot[blockIdx.x] = sd[255];
}

// ------- add block offsets; also emit packed per-node record rpd = {row_ptr, dinv bits} -------
__global__ void add_offsets(int* __restrict__ row_ptr, const int* __restrict__ block_tot,
                            const float* __restrict__ dinv, int2* __restrict__ rpd) {
    __shared__ int sd[256];
    int t = threadIdx.x;
    int blk = blockIdx.x;
    sd[t] = (t < blk && t < SCAN_NB) ? block_tot[t] : 0;
    __syncthreads();
    for (int off = 128; off > 0; off >>= 1) {
        if (t < off) sd[t] += sd[t + off];
        __syncthreads();
    }
    int base = sd[0];
    int idx = blk * 256 + t;
    if (idx < N_NODES) {
        int fin = row_ptr[idx] + base;
        row_ptr[idx] = fin;
        rpd[idx] = make_int2(fin, __float_as_int(dinv[idx]));
    }
    if (idx == 0) row_ptr[N_NODES] = N_EDGES;
}

// ======== FUSED: GEMM1 (blocks 0..ngemm-1) + atomic-free ILP-batched bucketing ========
// GEMM1: h8[M,256] = fp8( bf16(A) @ bf16(W) ), single MFMA per tile (W-lo dropped).
// Bucket: 4 edges/thread; pos = rpd[d].x + rank[e]; no atomics.
#define BM 64
#define BK 32
__global__ __launch_bounds__(256) void gemm1_bucket(
        const float* __restrict__ A,
        const short* __restrict__ Bthi,
        unsigned char* __restrict__ h8, int M,
        const int* __restrict__ src, const int* __restrict__ dst,
        const float* __restrict__ dinv, const int* __restrict__ rank,
        const int2* __restrict__ rpd, unsigned int* __restrict__ erec, int ngemm) {
    __shared__ short sAh[BM * BK];                     // 4KB
    __shared__ short sBh[256 * BK];                    // 16KB

    if (blockIdx.x >= ngemm) {
        // ---- bucket body: 4 edges/thread, all random loads issued in parallel ----
        int eb = (blockIdx.x - ngemm) * 1024 + threadIdx.x * 4;
        if (eb < N_EDGES) {
            int4 d4 = *(const int4*)&dst[eb];
            int4 s4 = *(const int4*)&src[eb];
            int4 r4 = *(const int4*)&rank[eb];
            int dd[4] = {d4.x, d4.y, d4.z, d4.w};
            int ss[4] = {s4.x, s4.y, s4.z, s4.w};
            int rk[4] = {r4.x, r4.y, r4.z, r4.w};
            int2 rd[4];
#pragma unroll
            for (int i = 0; i < 4; ++i) rd[i] = rpd[dd[i]];
            float dv[4];
#pragma unroll
            for (int i = 0; i < 4; ++i) dv[i] = dinv[ss[i]];
#pragma unroll
            for (int i = 0; i < 4; ++i) {
                unsigned int w = (unsigned int)f2bf(__int_as_float(rd[i].y) * dv[i]);
                erec[rd[i].x + rk[i]] = (unsigned int)ss[i] | (w << 16);
            }
        }
        return;
    }

    // ---- GEMM1 body ----
    int tid = threadIdx.x;
    int wave = tid >> 6, lane = tid & 63;
    int q = lane >> 4, t = lane & 15;
    int row0 = blockIdx.x * BM;
    int wc = wave * 64;            // wave's 64-col slice of N=256

    int lrow = lane >> 2;          // 0..15 (B staging)
    int lk = (lane & 3) * 8;       // k offset (shorts)
    int ar = tid >> 2;             // A staging: row 0..63
    int ak = (tid & 3) * 8;        // A staging: 8 floats at kt+ak

    int ga = row0 + ar; if (ga >= M) ga = M - 1;       // clamp; never stored
    const float* abase = &A[(size_t)ga * 256 + ak];
    float4 a0 = *(const float4*)(abase);
    float4 a1 = *(const float4*)(abase + 4);

    float4v acc[4][4] = {};
    for (int kt = 0; kt < 256; kt += BK) {
#pragma unroll
        for (int j = 0; j < 4; ++j) {
            int n = wave * 64 + j * 16 + lrow;
            size_t boff = (size_t)n * 256 + kt + lk;
            int ldso = wave * 2048 + j * 512 + lane * 8;
            gld_lds16(&Bthi[boff], &sBh[ldso]);
        }
        {
            short8 h;
            h[0] = (short)f2bf(a0.x); h[1] = (short)f2bf(a0.y);
            h[2] = (short)f2bf(a0.z); h[3] = (short)f2bf(a0.w);
            h[4] = (short)f2bf(a1.x); h[5] = (short)f2bf(a1.y);
            h[6] = (short)f2bf(a1.z); h[7] = (short)f2bf(a1.w);
            *(short8*)&sAh[ar * BK + ak] = h;
        }
        float4 na0 = a0, na1 = a1;
        if (kt + BK < 256) {
            na0 = *(const float4*)(abase + kt + BK);
            na1 = *(const float4*)(abase + kt + BK + 4);
        }
        __syncthreads();
        short8 ah[4], bh[4];
#pragma unroll
        for (int mi = 0; mi < 4; ++mi) {
            int r = mi * 16 + t;
            ah[mi] = *(const short8*)&sAh[r * BK + q * 8];
        }
#pragma unroll
        for (int ni = 0; ni < 4; ++ni) {
            int n = wc + ni * 16 + t;
            bh[ni] = *(const short8*)&sBh[n * BK + q * 8];
        }
#pragma unroll
        for (int mi = 0; mi < 4; ++mi)
#pragma unroll
            for (int ni = 0; ni < 4; ++ni)
                acc[mi][ni] = __builtin_amdgcn_mfma_f32_16x16x32_bf16(ah[mi], bh[ni], acc[mi][ni], 0, 0, 0);
        __syncthreads();
        a0 = na0; a1 = na1;
    }
#pragma unroll
    for (int mi = 0; mi < 4; ++mi) {
        int gr0 = row0 + mi * 16 + q * 4;
#pragma unroll
        for (int rr = 0; rr < 4; ++rr) {
            int gr = gr0 + rr;
            if (gr < M) {
#pragma unroll
                for (int ni = 0; ni < 4; ++ni)
                    h8[(size_t)gr * 256 + wc + ni * 16 + t] = fp8_enc(acc[mi][ni][rr]);
            }
        }
    }
}

// ---------------- GEMM2: bf16 A preloaded to regs; single MFMA; fp8 out ----------------
__global__ __launch_bounds__(256) void gemm_mfma_bf16(
        const ushort_t* __restrict__ A,   // [M,256] bf16
        const short* __restrict__ Bthi,
        unsigned char* __restrict__ h8, int M) {
    __shared__ short sA[BM * BK];                      // 4KB
    __shared__ short sBh[256 * BK];                    // 16KB
    int tid = threadIdx.x;
    int wave = tid >> 6, lane = tid & 63;
    int q = lane >> 4, t = lane & 15;
    int row0 = blockIdx.x * BM;
    int wc = wave * 64;

    int lrow = lane >> 2;          // 0..15 (B staging)
    int lk = (lane & 3) * 8;       // k offset (shorts)
    int ar = tid >> 2;             // A staging: row 0..63
    int ak = (tid & 3) * 8;        // 8 shorts at kt+ak

    int ga = row0 + ar; if (ga >= M) ga = M - 1;
    const ushort_t* abase = &A[(size_t)ga * 256 + ak];
    ushort8 areg[8];
#pragma unroll
    for (int i = 0; i < 8; ++i) areg[i] = *(const ushort8*)(abase + i * BK);

    float4v acc[4][4] = {};
#pragma unroll
    for (int ki = 0; ki < 8; ++ki) {
        int kt = ki * BK;
#pragma unroll
        for (int j = 0; j < 4; ++j) {
            int n = wave * 64 + j * 16 + lrow;
            size_t boff = (size_t)n * 256 + kt + lk;
            int ldso = wave * 2048 + j * 512 + lane * 8;
            gld_lds16(&Bthi[boff], &sBh[ldso]);
        }
        *(ushort8*)&sA[ar * BK + ak] = areg[ki];
        __syncthreads();
        short8 ah[4], bh[4];
#pragma unroll
        for (int mi = 0; mi < 4; ++mi) {
            int r = mi * 16 + t;
            ah[mi] = *(const short8*)&sA[r * BK + q * 8];
        }
#pragma unroll
        for (int ni = 0; ni < 4; ++ni) {
            int n = wc + ni * 16 + t;
            bh[ni] = *(const short8*)&sBh[n * BK + q * 8];
        }
#pragma unroll
        for (int mi = 0; mi < 4; ++mi)
#pragma unroll
            for (int ni = 0; ni < 4; ++ni)
                acc[mi][ni] = __builtin_amdgcn_mfma_f32_16x16x32_bf16(ah[mi], bh[ni], acc[mi][ni], 0, 0, 0);
        __syncthreads();
    }
#pragma unroll
    for (int mi = 0; mi < 4; ++mi) {
        int gr0 = row0 + mi * 16 + q * 4;
#pragma unroll
        for (int rr = 0; rr < 4; ++rr) {
            int gr = gr0 + rr;
            if (gr < M) {
#pragma unroll
                for (int ni = 0; ni < 4; ++ni)
                    h8[(size_t)gr * 256 + wc + ni * 16 + t] = fp8_enc(acc[mi][ni][rr]);
            }
        }
    }
}

// -------- CSR gather over fp8 h; 4 groups x 16 lanes x 16 feats (16B), 4 edges in flight --------
__global__ __launch_bounds__(256) void gather_fp8(
        const int* __restrict__ row_ptr, const unsigned int* __restrict__ erec,
        const float* __restrict__ dinv,
        const unsigned char* __restrict__ h8, const float* __restrict__ b,
        ushort_t* __restrict__ outBf) {
    int wave = threadIdx.x >> 6;
    int node = blockIdx.x * 4 + wave;      // N_NODES % 4 == 0
    int lane = threadIdx.x & 63;
    int g = lane >> 4;                      // 4 edge groups
    int hl = lane & 15;                     // feats hl*16 .. +15 (16 fp8 = 16B)
    int beg = row_ptr[node], end = row_ptr[node + 1];
    float dd = dinv[node];
    float acc[16] = {};
    for (int cbeg = beg; cbeg < end; cbeg += 64) {
        int n = end - cbeg; if (n > 64) n = 64;
        unsigned int ev = 0u;
        if (lane < n) ev = __builtin_nontemporal_load(&erec[cbeg + lane]);
        int niter = (n + 15) & ~15;         // pad to x16; pads contribute 0
        for (int k = 0; k < niter; k += 16) {
            unsigned int er0 = (unsigned int)__shfl((int)ev, k + g);
            unsigned int er1 = (unsigned int)__shfl((int)ev, k + 4 + g);
            unsigned int er2 = (unsigned int)__shfl((int)ev, k + 8 + g);
            unsigned int er3 = (unsigned int)__shfl((int)ev, k + 12 + g);
            uint4v p0 = *(const uint4v*)&h8[(size_t)((er0 & 0xFFFFu) * 256u + (unsigned)hl * 16u)];
            uint4v p1 = *(const uint4v*)&h8[(size_t)((er1 & 0xFFFFu) * 256u + (unsigned)hl * 16u)];
            uint4v p2 = *(const uint4v*)&h8[(size_t)((er2 & 0xFFFFu) * 256u + (unsigned)hl * 16u)];
            uint4v p3 = *(const uint4v*)&h8[(size_t)((er3 & 0xFFFFu) * 256u + (unsigned)hl * 16u)];
            float w0 = bf2f((unsigned short)(er0 >> 16));
            float w1 = bf2f((unsigned short)(er1 >> 16));
            float w2 = bf2f((unsigned short)(er2 >> 16));
            float w3 = bf2f((unsigned short)(er3 >> 16));
            float d0[4], d1[4], d2[4], d3[4];
#pragma unroll
            for (int wdi = 0; wdi < 4; ++wdi) {
                fp8x4_dec(p0[wdi], d0);
                fp8x4_dec(p1[wdi], d1);
                fp8x4_dec(p2[wdi], d2);
                fp8x4_dec(p3[wdi], d3);
#pragma unroll
                for (int j = 0; j < 4; ++j) {
                    int a = wdi * 4 + j;
                    acc[a] = fmaf(d0[j], w0, acc[a]);
                    acc[a] = fmaf(d1[j], w1, acc[a]);
                    acc[a] = fmaf(d2[j], w2, acc[a]);
                    acc[a] = fmaf(d3[j], w3, acc[a]);
                }
            }
        }
    }
#pragma unroll
    for (int j = 0; j < 16; ++j) {
        acc[j] += __shfl_xor(acc[j], 16);
        acc[j] += __shfl_xor(acc[j], 32);
    }
    if (g == 0) {
        uint4v sp = *(const uint4v*)&h8[(size_t)node * 256 + hl * 16];
        float sf[16];
        fp8x4_dec(sp[0], &sf[0]);
        fp8x4_dec(sp[1], &sf[4]);
        fp8x4_dec(sp[2], &sf[8]);
        fp8x4_dec(sp[3], &sf[12]);
        float4 b0 = *(const float4*)&b[hl * 16];
        float4 b1 = *(const float4*)&b[hl * 16 + 4];
        float4 b2 = *(const float4*)&b[hl * 16 + 8];
        float4 b3 = *(const float4*)&b[hl * 16 + 12];
        float bb[16] = {b0.x, b0.y, b0.z, b0.w, b1.x, b1.y, b1.z, b1.w,
                        b2.x, b2.y, b2.z, b2.w, b3.x, b3.y, b3.z, b3.w};
        float ws = dd * dd;
        ushort8 o0, o1;
#pragma unroll
        for (int j = 0; j < 8; ++j) {
            float v0 = fmaxf(fmaf(sf[j], ws, acc[j]) + bb[j], 0.f);
            o0[j] = f2bf(v0);
            float v1 = fmaxf(fmaf(sf[8 + j], ws, acc[8 + j]) + bb[8 + j], 0.f);
            o1[j] = f2bf(v1);
        }
        __builtin_nontemporal_store(o0, (ushort8*)&outBf[(size_t)node * 256 + hl * 16]);
        __builtin_nontemporal_store(o1, (ushort8*)&outBf[(size_t)node * 256 + hl * 16 + 8]);
    }
}

// ---------------- parallel triple pooling over bf16 h (1 wave/block) ----------------
__global__ __launch_bounds__(64) void pool_partial(
        const ushort_t* __restrict__ h, const int* __restrict__ batch,
        float* __restrict__ psum, int* __restrict__ pmaxi) {
    int g = blockIdx.x;
    int chunk = blockIdx.y;
    int lane = threadIdx.x;  // 64; lane covers feats lane*4..lane*4+3
    int lo = 0, hi = N_NODES;
    while (lo < hi) { int mid = (lo + hi) >> 1; if (batch[mid] < g) lo = mid + 1; else hi = mid; }
    int start = lo;
    lo = 0; hi = N_NODES;
    while (lo < hi) { int mid = (lo + hi) >> 1; if (batch[mid] < g + 1) lo = mid + 1; else hi = mid; }
    int end = lo;
    int len = end - start;
    if (len <= 0) return;
    int per = (len + POOL_CHUNKS - 1) / POOL_CHUNKS;
    int cs = start + chunk * per;
    int ce = cs + per; if (ce > end) ce = end;
    if (cs >= ce) return;
    float4 sum = make_float4(0.f, 0.f, 0.f, 0.f);
    float4 mx  = make_float4(0.f, 0.f, 0.f, 0.f);
    for (int n = cs; n < ce; ++n) {
        ushort4v u = *(const ushort4v*)&h[(size_t)n * 256 + lane * 4];
        float vx = bf2f(u.x), vy = bf2f(u.y), vz = bf2f(u.z), vw = bf2f(u.w);
        sum.x += vx; sum.y += vy; sum.z += vz; sum.w += vw;
        mx.x = fmaxf(mx.x, vx); mx.y = fmaxf(mx.y, vy);
        mx.z = fmaxf(mx.z, vz); mx.w = fmaxf(mx.w, vw);
    }
    float* ps = &psum[g * F + lane * 4];
    atomicAdd(&ps[0], sum.x); atomicAdd(&ps[1], sum.y);
    atomicAdd(&ps[2], sum.z); atomicAdd(&ps[3], sum.w);
    int* pm = &pmaxi[g * F + lane * 4];
    atomicMax(&pm[0], __float_as_int(mx.x)); atomicMax(&pm[1], __float_as_int(mx.y));
    atomicMax(&pm[2], __float_as_int(mx.z)); atomicMax(&pm[3], __float_as_int(mx.w));
}

// ---------------- final GEMM: out[64,128] = [mean|max|sum] @ Wfc + bfc ----------------
__global__ void final_gemm(const float* __restrict__ psum, const int* __restrict__ pmaxi,
                           const int* __restrict__ batch,
                           const float* __restrict__ Wfc, const float* __restrict__ bfc,
                           float* __restrict__ out) {
    int g = blockIdx.x;   // 64
    int o = threadIdx.x;  // 128
    __shared__ float row[G_DIM];
    __shared__ int s_cnt;
    if (threadIdx.x == 0) {
        int lo = 0, hi = N_NODES;
        while (lo < hi) { int mid = (lo + hi) >> 1; if (batch[mid] < g) lo = mid + 1; else hi = mid; }
        int start = lo;
        lo = 0; hi = N_NODES;
        while (lo < hi) { int mid = (lo + hi) >> 1; if (batch[mid] < g + 1) lo = mid + 1; else hi = mid; }
        s_cnt = lo - start;
    }
    __syncthreads();
    float inv = 1.0f / fmaxf((float)s_cnt, 1.0f);
    for (int i = threadIdx.x; i < F; i += 128) {
        float s = psum[g * F + i];
        row[i]       = s * inv;
        row[F + i]   = __int_as_float(pmaxi[g * F + i]);
        row[2*F + i] = s;
    }
    __syncthreads();
    float acc = bfc[o];
    for (int k = 0; k < G_DIM; ++k) acc += row[k] * Wfc[k * F_OUT + o];
    out[g * F_OUT + o] = acc;
}

extern "C" void kernel_launch(void* const* d_in, const int* in_sizes, int n_in,
                              void* d_out, int out_size, void* d_ws, size_t ws_size,
                              hipStream_t stream) {
    const float* x    = (const float*)d_in[0];
    const int*   ei   = (const int*)d_in[1];
    const int*   batch= (const int*)d_in[2];
    const float* W1   = (const float*)d_in[4];
    const float* b1   = (const float*)d_in[5];
    const float* W2   = (const float*)d_in[6];
    const float* b2   = (const float*)d_in[7];
    const float* Wfc  = (const float*)d_in[8];
    const float* bfc  = (const float*)d_in[9];
    float* out = (float*)d_out;

    const int* src = ei;
    const int* dst = ei + N_EDGES;

    const size_t NF = (size_t)N_NODES * F;   // 12.8M

    unsigned char* h8 = (unsigned char*)d_ws;   // [N,256] fp8 gemm out (12.8 MB)
    ushort_t* h1bf = (ushort_t*)(h8 + NF);      // [N,256] bf16 gather1 out; reused as h2bf
    ushort_t* h2bf = h1bf;                      //   (h1 consumed by gemm2 before gather2 writes)
    short* w1hi  = (short*)(h1bf + NF);         // 2x 64K shorts (hi only)
    short* w2hi  = w1hi + 65536;
    float* dinv  = (float*)(w2hi + 65536);   // [N]
    // ---- contiguous zero-init region: deg, psum, pmaxi ----
    int*   deg   = (int*)(dinv + N_NODES);       // [N]
    float* psum  = (float*)(deg + N_NODES);      // [64][256]
    int*   pmaxi = (int*)(psum + N_GRAPHS * F);  // [64][256]
    // ---- rest (all fully overwritten each run; no init needed) ----
    int2*  rpd   = (int2*)(pmaxi + N_GRAPHS * F);   // [N] {row_ptr, dinv bits} (8B aligned)
    int*   row_ptr = (int*)(rpd + N_NODES);      // [N+1]
    int*   btot  = row_ptr + N_NODES + 1;        // [256]
    unsigned int* erec = (unsigned int*)(btot + 256 + 1);   // [E] 4B records (3.2 MB)
    int*   rank  = (int*)(erec + N_EDGES);       // [E] per-edge rank at dst (3.2 MB)

    // ---- degree + rank + norm + CSR prep (+ W casts fused) ----
    hipMemsetAsync(deg, 0, (N_NODES + 2 * N_GRAPHS * F) * sizeof(int), stream);
    prep_w_deg<<<512 + EBLK4, 256, 0, stream>>>(
        W1, W2, w1hi, w2hi, dst, deg, rank);
    scan_blocks<<<SCAN_NB, 256, 0, stream>>>(deg, row_ptr, btot, dinv);
    add_offsets<<<SCAN_NB, 256, 0, stream>>>(row_ptr, btot, dinv, rpd);

    int ggemm = (N_NODES + BM - 1) / BM;      // 782
    int ngb = N_NODES / 4;                    // 12500 blocks of 4 waves

    // ---- layer 1 (GEMM fused with atomic-free ILP-batched bucketing) ----
    gemm1_bucket<<<ggemm + EBLK4, 256, 0, stream>>>(
        x, w1hi, h8, N_NODES, src, dst, dinv, rank, rpd, erec, ggemm);
    gather_fp8<<<ngb, 256, 0, stream>>>(row_ptr, erec, dinv, h8, b1, h1bf);

    // ---- layer 2 ----
    gemm_mfma_bf16<<<ggemm, 256, 0, stream>>>(h1bf, w2hi, h8, N_NODES);
    gather_fp8<<<ngb, 256, 0, stream>>>(row_ptr, erec, dinv, h8, b2, h2bf);

    // ---- pooling + classifier ----
    pool_partial<<<dim3(N_GRAPHS, POOL_CHUNKS), 64, 0, stream>>>(h2bf, batch, psum, pmaxi);
    final_gemm<<<N_GRAPHS, F_OUT, 0, stream>>>(psum, pmaxi, batch, Wfc, bfc, out);
}

// Round 10
// 309.062 us; speedup vs baseline: 1.9758x; 1.0030x over previous
//
#include <hip/hip_runtime.h>

#define N_NODES 50000
#define N_EDGES 800000
#define N_GRAPHS 64
#define F 256        // F_IN == F_HID
#define F_OUT 128
#define G_DIM 768    // 3*F
#define SCAN_NB ((N_NODES + 255) / 256)   // 196
#define POOL_CHUNKS 32
#define EBLK4 ((N_EDGES + 1023) / 1024)   // 782 (4 edges/thread)

typedef unsigned short ushort_t;
typedef short short8 __attribute__((ext_vector_type(8)));
typedef unsigned short ushort8 __attribute__((ext_vector_type(8)));
typedef unsigned short ushort4v __attribute__((ext_vector_type(4)));
typedef float float4v __attribute__((ext_vector_type(4)));
typedef float f32x2 __attribute__((ext_vector_type(2)));
typedef unsigned int uint4v __attribute__((ext_vector_type(4)));
typedef unsigned int uint2v __attribute__((ext_vector_type(2)));

// ---- bf16 helpers (RNE) ----
__device__ __forceinline__ unsigned short f2bf(float f) {
    unsigned int u = __float_as_uint(f);
    u += 0x7FFFu + ((u >> 16) & 1u);
    return (unsigned short)(u >> 16);
}
__device__ __forceinline__ float bf2f(unsigned short s) {
    return __uint_as_float(((unsigned int)s) << 16);
}

// ---- fp8 e4m3 encode/decode: HW cvt when available, exact bit-trick fallback ----
__device__ __forceinline__ unsigned char fp8_enc(float v) {
#if __has_builtin(__builtin_amdgcn_cvt_pk_fp8_f32)
    return (unsigned char)__builtin_amdgcn_cvt_pk_fp8_f32(v, v, 0, false);
#else
    float x = v * 0x1p-120f;                    // align e4m3 to f32 bits 27..20
    unsigned int u = __float_as_uint(x);
    unsigned int mag = u & 0x7FFFFFFFu;
    unsigned int r = mag + 0x0007FFFFu + ((mag >> 20) & 1u);   // RNE at bit 20
    unsigned int em = r >> 20;
    if (em > 0x7Eu) em = 0x7Eu;                 // clamp to +-448, no NaN
    return (unsigned char)(em | ((u >> 24) & 0x80u));
#endif
}

// decode 4 fp8 (one u32) -> 4 floats
__device__ __forceinline__ void fp8x4_dec(unsigned int u, float* o) {
#if __has_builtin(__builtin_amdgcn_cvt_pk_f32_fp8)
    f32x2 d0 = __builtin_amdgcn_cvt_pk_f32_fp8((int)u, false);
    f32x2 d1 = __builtin_amdgcn_cvt_pk_f32_fp8((int)u, true);
    o[0] = d0[0]; o[1] = d0[1]; o[2] = d1[0]; o[3] = d1[1];
#else
#pragma unroll
    for (int i = 0; i < 4; ++i) {
        unsigned int b = (u >> (8 * i)) & 0xFFu;
        unsigned int bits = ((b & 0x7Fu) << 20) | ((b & 0x80u) << 24);
        o[i] = __uint_as_float(bits) * 0x1p+120f;   // exact incl. subnormals
    }
#endif
}

// ---- async global->LDS, 16B per lane; LDS dest = wave-uniform base + lane*16 ----
__device__ __forceinline__ void gld_lds16(const void* gsrc, void* ldst) {
    __builtin_amdgcn_global_load_lds(
        (const __attribute__((address_space(1))) unsigned int*)gsrc,
        (__attribute__((address_space(3))) unsigned int*)ldst, 16, 0, 0);
}

// ------- fused: W1/W2 transposed bf16 cast (blocks 0..511) + deg count + edge rank -------
__global__ void prep_w_deg(const float* __restrict__ W1, const float* __restrict__ W2,
                           short* __restrict__ hi1, short* __restrict__ hi2,
                           const int* __restrict__ dst, int* __restrict__ deg,
                           int* __restrict__ rank) {
    int blk = blockIdx.x;
    if (blk < 512) {
        const float* W = (blk < 256) ? W1 : W2;
        short* hi = (blk < 256) ? hi1 : hi2;
        int n = blk & 255;
        int k = threadIdx.x;
        hi[n * 256 + k] = (short)f2bf(W[k * 256 + n]);
    } else {
        int eb = (blk - 512) * 1024 + threadIdx.x * 4;
        if (eb < N_EDGES) {                       // N_EDGES%4==0 -> int4 safe
            int4 d4 = *(const int4*)&dst[eb];
            int r0 = atomicAdd(&deg[d4.x], 1);
            int r1 = atomicAdd(&deg[d4.y], 1);
            int r2 = atomicAdd(&deg[d4.z], 1);
            int r3 = atomicAdd(&deg[d4.w], 1);
            *(int4*)&rank[eb] = make_int4(r0, r1, r2, r3);
        }
    }
}

// ---------------- scan blocks + fused dinv (btot holds RAW per-block sums) ----------------
__global__ void scan_blocks(const int* __restrict__ deg, int* __restrict__ row_ptr,
                            int* __restrict__ block_tot, float* __restrict__ dinv) {
    __shared__ int sd[256];
    int t = threadIdx.x;
    int idx = blockIdx.x * 256 + t;
    int v = (idx < N_NODES) ? deg[idx] : 0;
    if (idx < N_NODES) dinv[idx] = rsqrtf((float)(v + 1));   // +1 self-loop
    sd[t] = v;
    __syncthreads();
    for (int off = 1; off < 256; off <<= 1) {
        int a = (t >= off) ? sd[t - off] : 0;
        __syncthreads();
        sd[t] += a;
        __syncthreads();
    }
    if (idx < N_NODES) row_ptr[idx] = sd[t] - v;
    if (t == 255) block_tot[blockIdx.x] = sd[255];
}

// ------- add block offsets; also emit packed per-node record rpd = {row_ptr, dinv bits} -------
__global__ void add_offsets(int* __restrict__ row_ptr, const int* __restrict__ block_tot,
                            const float* __restrict__ dinv, int2* __restrict__ rpd) {
    __shared__ int sd[256];
    int t = threadIdx.x;
    int blk = blockIdx.x;
    sd[t] = (t < blk && t < SCAN_NB) ? block_tot[t] : 0;
    __syncthreads();
    for (int off = 128; off > 0; off >>= 1) {
        if (t < off) sd[t] += sd[t + off];
        __syncthreads();
    }
    int base = sd[0];
    int idx = blk * 256 + t;
    if (idx < N_NODES) {
        int fin = row_ptr[idx] + base;
        row_ptr[idx] = fin;
        rpd[idx] = make_int2(fin, __float_as_int(dinv[idx]));
    }
    if (idx == 0) row_ptr[N_NODES] = N_EDGES;
}

// ======== FUSED: GEMM1 (blocks 0..ngemm-1) + atomic-free ILP-batched bucketing ========
#define BM 64
#define BK 32
__global__ __launch_bounds__(256) void gemm1_bucket(
        const float* __restrict__ A,
        const short* __restrict__ Bthi,
        unsigned char* __restrict__ h8, int M,
        const int* __restrict__ src, const int* __restrict__ dst,
        const float* __restrict__ dinv, const int* __restrict__ rank,
        const int2* __restrict__ rpd, unsigned int* __restrict__ erec, int ngemm) {
    __shared__ short sAh[BM * BK];                     // 4KB
    __shared__ short sBh[256 * BK];                    // 16KB

    if (blockIdx.x >= ngemm) {
        // ---- bucket body: 4 edges/thread, all random loads issued in parallel ----
        int eb = (blockIdx.x - ngemm) * 1024 + threadIdx.x * 4;
        if (eb < N_EDGES) {
            int4 d4 = *(const int4*)&dst[eb];
            int4 s4 = *(const int4*)&src[eb];
            int4 r4 = *(const int4*)&rank[eb];
            int dd[4] = {d4.x, d4.y, d4.z, d4.w};
            int ss[4] = {s4.x, s4.y, s4.z, s4.w};
            int rk[4] = {r4.x, r4.y, r4.z, r4.w};
            int2 rd[4];
#pragma unroll
            for (int i = 0; i < 4; ++i) rd[i] = rpd[dd[i]];
            float dv[4];
#pragma unroll
            for (int i = 0; i < 4; ++i) dv[i] = dinv[ss[i]];
#pragma unroll
            for (int i = 0; i < 4; ++i) {
                unsigned int w = (unsigned int)f2bf(__int_as_float(rd[i].y) * dv[i]);
                erec[rd[i].x + rk[i]] = (unsigned int)ss[i] | (w << 16);
            }
        }
        return;
    }

    // ---- GEMM1 body ----
    int tid = threadIdx.x;
    int wave = tid >> 6, lane = tid & 63;
    int q = lane >> 4, t = lane & 15;
    int row0 = blockIdx.x * BM;
    int wc = wave * 64;            // wave's 64-col slice of N=256

    int lrow = lane >> 2;          // 0..15 (B staging)
    int lk = (lane & 3) * 8;       // k offset (shorts)
    int ar = tid >> 2;             // A staging: row 0..63
    int ak = (tid & 3) * 8;        // A staging: 8 floats at kt+ak

    int ga = row0 + ar; if (ga >= M) ga = M - 1;       // clamp; never stored
    const float* abase = &A[(size_t)ga * 256 + ak];
    float4 a0 = *(const float4*)(abase);
    float4 a1 = *(const float4*)(abase + 4);

    float4v acc[4][4] = {};
    for (int kt = 0; kt < 256; kt += BK) {
#pragma unroll
        for (int j = 0; j < 4; ++j) {
            int n = wave * 64 + j * 16 + lrow;
            size_t boff = (size_t)n * 256 + kt + lk;
            int ldso = wave * 2048 + j * 512 + lane * 8;
            gld_lds16(&Bthi[boff], &sBh[ldso]);
        }
        {
            short8 h;
            h[0] = (short)f2bf(a0.x); h[1] = (short)f2bf(a0.y);
            h[2] = (short)f2bf(a0.z); h[3] = (short)f2bf(a0.w);
            h[4] = (short)f2bf(a1.x); h[5] = (short)f2bf(a1.y);
            h[6] = (short)f2bf(a1.z); h[7] = (short)f2bf(a1.w);
            *(short8*)&sAh[ar * BK + ak] = h;
        }
        float4 na0 = a0, na1 = a1;
        if (kt + BK < 256) {
            na0 = *(const float4*)(abase + kt + BK);
            na1 = *(const float4*)(abase + kt + BK + 4);
        }
        __syncthreads();
        short8 ah[4], bh[4];
#pragma unroll
        for (int mi = 0; mi < 4; ++mi) {
            int r = mi * 16 + t;
            ah[mi] = *(const short8*)&sAh[r * BK + q * 8];
        }
#pragma unroll
        for (int ni = 0; ni < 4; ++ni) {
            int n = wc + ni * 16 + t;
            bh[ni] = *(const short8*)&sBh[n * BK + q * 8];
        }
#pragma unroll
        for (int mi = 0; mi < 4; ++mi)
#pragma unroll
            for (int ni = 0; ni < 4; ++ni)
                acc[mi][ni] = __builtin_amdgcn_mfma_f32_16x16x32_bf16(ah[mi], bh[ni], acc[mi][ni], 0, 0, 0);
        __syncthreads();
        a0 = na0; a1 = na1;
    }
#pragma unroll
    for (int mi = 0; mi < 4; ++mi) {
        int gr0 = row0 + mi * 16 + q * 4;
#pragma unroll
        for (int rr = 0; rr < 4; ++rr) {
            int gr = gr0 + rr;
            if (gr < M) {
#pragma unroll
                for (int ni = 0; ni < 4; ++ni)
                    h8[(size_t)gr * 256 + wc + ni * 16 + t] = fp8_enc(acc[mi][ni][rr]);
            }
        }
    }
}

// ---------------- GEMM2: fp8 A decoded to bf16 in staging; single MFMA; fp8 out ----------------
__global__ __launch_bounds__(256) void gemm_mfma_fp8a(
        const unsigned char* __restrict__ A,   // [M,256] fp8
        const short* __restrict__ Bthi,
        unsigned char* __restrict__ h8, int M) {
    __shared__ short sA[BM * BK];                      // 4KB
    __shared__ short sBh[256 * BK];                    // 16KB
    int tid = threadIdx.x;
    int wave = tid >> 6, lane = tid & 63;
    int q = lane >> 4, t = lane & 15;
    int row0 = blockIdx.x * BM;
    int wc = wave * 64;

    int lrow = lane >> 2;          // 0..15 (B staging)
    int lk = (lane & 3) * 8;       // k offset (shorts)
    int ar = tid >> 2;             // A staging: row 0..63
    int ak = (tid & 3) * 8;        // 8 elements at kt+ak (elements == bytes for fp8)

    int ga = row0 + ar; if (ga >= M) ga = M - 1;
    const unsigned char* abase = &A[(size_t)ga * 256 + ak];
    // preload this thread's 64 fp8 bytes (8 x 8B, all issued together)
    uint2v areg[8];
#pragma unroll
    for (int i = 0; i < 8; ++i) areg[i] = *(const uint2v*)(abase + i * BK);

    float4v acc[4][4] = {};
#pragma unroll
    for (int ki = 0; ki < 8; ++ki) {
        int kt = ki * BK;
#pragma unroll
        for (int j = 0; j < 4; ++j) {
            int n = wave * 64 + j * 16 + lrow;
            size_t boff = (size_t)n * 256 + kt + lk;
            int ldso = wave * 2048 + j * 512 + lane * 8;
            gld_lds16(&Bthi[boff], &sBh[ldso]);
        }
        {
            float f0[4], f1[4];
            fp8x4_dec(areg[ki][0], f0);
            fp8x4_dec(areg[ki][1], f1);
            short8 h;
            h[0] = (short)f2bf(f0[0]); h[1] = (short)f2bf(f0[1]);
            h[2] = (short)f2bf(f0[2]); h[3] = (short)f2bf(f0[3]);
            h[4] = (short)f2bf(f1[0]); h[5] = (short)f2bf(f1[1]);
            h[6] = (short)f2bf(f1[2]); h[7] = (short)f2bf(f1[3]);
            *(short8*)&sA[ar * BK + ak] = h;
        }
        __syncthreads();
        short8 ah[4], bh[4];
#pragma unroll
        for (int mi = 0; mi < 4; ++mi) {
            int r = mi * 16 + t;
            ah[mi] = *(const short8*)&sA[r * BK + q * 8];
        }
#pragma unroll
        for (int ni = 0; ni < 4; ++ni) {
            int n = wc + ni * 16 + t;
            bh[ni] = *(const short8*)&sBh[n * BK + q * 8];
        }
#pragma unroll
        for (int mi = 0; mi < 4; ++mi)
#pragma unroll
            for (int ni = 0; ni < 4; ++ni)
                acc[mi][ni] = __builtin_amdgcn_mfma_f32_16x16x32_bf16(ah[mi], bh[ni], acc[mi][ni], 0, 0, 0);
        __syncthreads();
    }
#pragma unroll
    for (int mi = 0; mi < 4; ++mi) {
        int gr0 = row0 + mi * 16 + q * 4;
#pragma unroll
        for (int rr = 0; rr < 4; ++rr) {
            int gr = gr0 + rr;
            if (gr < M) {
#pragma unroll
                for (int ni = 0; ni < 4; ++ni)
                    h8[(size_t)gr * 256 + wc + ni * 16 + t] = fp8_enc(acc[mi][ni][rr]);
            }
        }
    }
}

// -------- CSR gather over fp8 h; fp8 OUT (halves write + downstream read) --------
__global__ __launch_bounds__(256) void gather_fp8(
        const int* __restrict__ row_ptr, const unsigned int* __restrict__ erec,
        const float* __restrict__ dinv,
        const unsigned char* __restrict__ h8, const float* __restrict__ b,
        unsigned char* __restrict__ out8) {
    int wave = threadIdx.x >> 6;
    int node = blockIdx.x * 4 + wave;      // N_NODES % 4 == 0
    int lane = threadIdx.x & 63;
    int g = lane >> 4;                      // 4 edge groups
    int hl = lane & 15;                     // feats hl*16 .. +15 (16 fp8 = 16B)
    int beg = row_ptr[node], end = row_ptr[node + 1];
    float dd = dinv[node];
    float acc[16] = {};
    for (int cbeg = beg; cbeg < end; cbeg += 64) {
        int n = end - cbeg; if (n > 64) n = 64;
        unsigned int ev = 0u;
        if (lane < n) ev = __builtin_nontemporal_load(&erec[cbeg + lane]);
        int niter = (n + 15) & ~15;         // pad to x16; pads contribute 0
        for (int k = 0; k < niter; k += 16) {
            unsigned int er0 = (unsigned int)__shfl((int)ev, k + g);
            unsigned int er1 = (unsigned int)__shfl((int)ev, k + 4 + g);
            unsigned int er2 = (unsigned int)__shfl((int)ev, k + 8 + g);
            unsigned int er3 = (unsigned int)__shfl((int)ev, k + 12 + g);
            uint4v p0 = *(const uint4v*)&h8[(size_t)((er0 & 0xFFFFu) * 256u + (unsigned)hl * 16u)];
            uint4v p1 = *(const uint4v*)&h8[(size_t)((er1 & 0xFFFFu) * 256u + (unsigned)hl * 16u)];
            uint4v p2 = *(const uint4v*)&h8[(size_t)((er2 & 0xFFFFu) * 256u + (unsigned)hl * 16u)];
            uint4v p3 = *(const uint4v*)&h8[(size_t)((er3 & 0xFFFFu) * 256u + (unsigned)hl * 16u)];
            float w0 = bf2f((unsigned short)(er0 >> 16));
            float w1 = bf2f((unsigned short)(er1 >> 16));
            float w2 = bf2f((unsigned short)(er2 >> 16));
            float w3 = bf2f((unsigned short)(er3 >> 16));
            float d0[4], d1[4], d2[4], d3[4];
#pragma unroll
            for (int wdi = 0; wdi < 4; ++wdi) {
                fp8x4_dec(p0[wdi], d0);
                fp8x4_dec(p1[wdi], d1);
                fp8x4_dec(p2[wdi], d2);
                fp8x4_dec(p3[wdi], d3);
#pragma unroll
                for (int j = 0; j < 4; ++j) {
                    int a = wdi * 4 + j;
                    acc[a] = fmaf(d0[j], w0, acc[a]);
                    acc[a] = fmaf(d1[j], w1, acc[a]);
                    acc[a] = fmaf(d2[j], w2, acc[a]);
                    acc[a] = fmaf(d3[j], w3, acc[a]);
                }
            }
        }
    }
#pragma unroll
    for (int j = 0; j < 16; ++j) {
        acc[j] += __shfl_xor(acc[j], 16);
        acc[j] += __shfl_xor(acc[j], 32);
    }
    if (g == 0) {
        uint4v sp = *(const uint4v*)&h8[(size_t)node * 256 + hl * 16];
        float sf[16];
        fp8x4_dec(sp[0], &sf[0]);
        fp8x4_dec(sp[1], &sf[4]);
        fp8x4_dec(sp[2], &sf[8]);
        fp8x4_dec(sp[3], &sf[12]);
        float4 b0 = *(const float4*)&b[hl * 16];
        float4 b1 = *(const float4*)&b[hl * 16 + 4];
        float4 b2 = *(const float4*)&b[hl * 16 + 8];
        float4 b3 = *(const float4*)&b[hl * 16 + 12];
        float bb[16] = {b0.x, b0.y, b0.z, b0.w, b1.x, b1.y, b1.z, b1.w,
                        b2.x, b2.y, b2.z, b2.w, b3.x, b3.y, b3.z, b3.w};
        float ws = dd * dd;
        uint4v o;
#pragma unroll
        for (int wd = 0; wd < 4; ++wd) {
            unsigned int packed = 0;
#pragma unroll
            for (int j = 0; j < 4; ++j) {
                int a = wd * 4 + j;
                float v = fmaxf(fmaf(sf[a], ws, acc[a]) + bb[a], 0.f);
                packed |= ((unsigned int)fp8_enc(v)) << (8 * j);
            }
            o[wd] = packed;
        }
        __builtin_nontemporal_store(o, (uint4v*)&out8[(size_t)node * 256 + hl * 16]);
    }
}

// ---------------- parallel triple pooling over fp8 h (1 wave/block) ----------------
__global__ __launch_bounds__(64) void pool_partial(
        const unsigned char* __restrict__ h, const int* __restrict__ batch,
        float* __restrict__ psum, int* __restrict__ pmaxi) {
    int g = blockIdx.x;
    int chunk = blockIdx.y;
    int lane = threadIdx.x;  // 64; lane covers feats lane*4..lane*4+3
    int lo = 0, hi = N_NODES;
    while (lo < hi) { int mid = (lo + hi) >> 1; if (batch[mid] < g) lo = mid + 1; else hi = mid; }
    int start = lo;
    lo = 0; hi = N_NODES;
    while (lo < hi) { int mid = (lo + hi) >> 1; if (batch[mid] < g + 1) lo = mid + 1; else hi = mid; }
    int end = lo;
    int len = end - start;
    if (len <= 0) return;
    int per = (len + POOL_CHUNKS - 1) / POOL_CHUNKS;
    int cs = start + chunk * per;
    int ce = cs + per; if (ce > end) ce = end;
    if (cs >= ce) return;
    float4 sum = make_float4(0.f, 0.f, 0.f, 0.f);
    float4 mx  = make_float4(0.f, 0.f, 0.f, 0.f);
    for (int n = cs; n < ce; ++n) {
        unsigned int u = *(const unsigned int*)&h[(size_t)n * 256 + lane * 4];
        float f[4];
        fp8x4_dec(u, f);
        sum.x += f[0]; sum.y += f[1]; sum.z += f[2]; sum.w += f[3];
        mx.x = fmaxf(mx.x, f[0]); mx.y = fmaxf(mx.y, f[1]);
        mx.z = fmaxf(mx.z, f[2]); mx.w = fmaxf(mx.w, f[3]);
    }
    float* ps = &psum[g * F + lane * 4];
    atomicAdd(&ps[0], sum.x); atomicAdd(&ps[1], sum.y);
    atomicAdd(&ps[2], sum.z); atomicAdd(&ps[3], sum.w);
    int* pm = &pmaxi[g * F + lane * 4];
    atomicMax(&pm[0], __float_as_int(mx.x)); atomicMax(&pm[1], __float_as_int(mx.y));
    atomicMax(&pm[2], __float_as_int(mx.z)); atomicMax(&pm[3], __float_as_int(mx.w));
}

// ---------------- final GEMM: out[64,128] = [mean|max|sum] @ Wfc + bfc ----------------
__global__ void final_gemm(const float* __restrict__ psum, const int* __restrict__ pmaxi,
                           const int* __restrict__ batch,
                           const float* __restrict__ Wfc, const float* __restrict__ bfc,
                           float* __restrict__ out) {
    int g = blockIdx.x;   // 64
    int o = threadIdx.x;  // 128
    __shared__ float row[G_DIM];
    __shared__ int s_cnt;
    if (threadIdx.x == 0) {
        int lo = 0, hi = N_NODES;
        while (lo < hi) { int mid = (lo + hi) >> 1; if (batch[mid] < g) lo = mid + 1; else hi = mid; }
        int start = lo;
        lo = 0; hi = N_NODES;
        while (lo < hi) { int mid = (lo + hi) >> 1; if (batch[mid] < g + 1) lo = mid + 1; else hi = mid; }
        s_cnt = lo - start;
    }
    __syncthreads();
    float inv = 1.0f / fmaxf((float)s_cnt, 1.0f);
    for (int i = threadIdx.x; i < F; i += 128) {
        float s = psum[g * F + i];
        row[i]       = s * inv;
        row[F + i]   = __int_as_float(pmaxi[g * F + i]);
        row[2*F + i] = s;
    }
    __syncthreads();
    float acc = bfc[o];
    for (int k = 0; k < G_DIM; ++k) acc += row[k] * Wfc[k * F_OUT + o];
    out[g * F_OUT + o] = acc;
}

extern "C" void kernel_launch(void* const* d_in, const int* in_sizes, int n_in,
                              void* d_out, int out_size, void* d_ws, size_t ws_size,
                              hipStream_t stream) {
    const float* x    = (const float*)d_in[0];
    const int*   ei   = (const int*)d_in[1];
    const int*   batch= (const int*)d_in[2];
    const float* W1   = (const float*)d_in[4];
    const float* b1   = (const float*)d_in[5];
    const float* W2   = (const float*)d_in[6];
    const float* b2   = (const float*)d_in[7];
    const float* Wfc  = (const float*)d_in[8];
    const float* bfc  = (const float*)d_in[9];
    float* out = (float*)d_out;

    const int* src = ei;
    const int* dst = ei + N_EDGES;

    const size_t NF = (size_t)N_NODES * F;   // 12.8M

    unsigned char* h8   = (unsigned char*)d_ws;   // [N,256] fp8 gemm out (12.8 MB)
    unsigned char* h1_8 = h8 + NF;                // [N,256] fp8 gather1 out; reused as h2_8
    unsigned char* h2_8 = h1_8;                   //   (h1 consumed by gemm2 before gather2 writes)
    short* w1hi  = (short*)(h1_8 + NF);           // 2x 64K shorts (hi only)
    short* w2hi  = w1hi + 65536;
    float* dinv  = (float*)(w2hi + 65536);   // [N]
    // ---- contiguous zero-init region: deg, psum, pmaxi ----
    int*   deg   = (int*)(dinv + N_NODES);       // [N]
    float* psum  = (float*)(deg + N_NODES);      // [64][256]
    int*   pmaxi = (int*)(psum + N_GRAPHS * F);  // [64][256]
    // ---- rest (all fully overwritten each run; no init needed) ----
    int2*  rpd   = (int2*)(pmaxi + N_GRAPHS * F);   // [N] {row_ptr, dinv bits} (8B aligned)
    int*   row_ptr = (int*)(rpd + N_NODES);      // [N+1]
    int*   btot  = row_ptr + N_NODES + 1;        // [256]
    unsigned int* erec = (unsigned int*)(btot + 256 + 1);   // [E] 4B records (3.2 MB)
    int*   rank  = (int*)(erec + N_EDGES);       // [E] per-edge rank at dst (3.2 MB)

    // ---- degree + rank + norm + CSR prep (+ W casts fused) ----
    hipMemsetAsync(deg, 0, (N_NODES + 2 * N_GRAPHS * F) * sizeof(int), stream);
    prep_w_deg<<<512 + EBLK4, 256, 0, stream>>>(
        W1, W2, w1hi, w2hi, dst, deg, rank);
    scan_blocks<<<SCAN_NB, 256, 0, stream>>>(deg, row_ptr, btot, dinv);
    add_offsets<<<SCAN_NB, 256, 0, stream>>>(row_ptr, btot, dinv, rpd);

    int ggemm = (N_NODES + BM - 1) / BM;      // 782
    int ngb = N_NODES / 4;                    // 12500 blocks of 4 waves

    // ---- layer 1 (GEMM fused with atomic-free ILP-batched bucketing) ----
    gemm1_bucket<<<ggemm + EBLK4, 256, 0, stream>>>(
        x, w1hi, h8, N_NODES, src, dst, dinv, rank, rpd, erec, ggemm);
    gather_fp8<<<ngb, 256, 0, stream>>>(row_ptr, erec, dinv, h8, b1, h1_8);

    // ---- layer 2 ----
    gemm_mfma_fp8a<<<ggemm, 256, 0, stream>>>(h1_8, w2hi, h8, N_NODES);
    gather_fp8<<<ngb, 256, 0, stream>>>(row_ptr, erec, dinv, h8, b2, h2_8);

    // ---- pooling + classifier ----
    pool_partial<<<dim3(N_GRAPHS, POOL_CHUNKS), 64, 0, stream>>>(h2_8, batch, psum, pmaxi);
    final_gemm<<<N_GRAPHS, F_OUT, 0, stream>>>(psum, pmaxi, batch, Wfc, bfc, out);
}